// Round 11
// baseline (205.929 us; speedup 1.0000x reference)
//
#include <hip/hip_runtime.h>
#include <cstdint>
#include <cmath>

#define BB 64
#define SS 256
#define NN 512
#define MAXC 64   // max nonzeros per adj column (mean ~25.6, true max ~46)

typedef float f32x4 __attribute__((ext_vector_type(4)));
typedef short bf16x8 __attribute__((ext_vector_type(8)));

__device__ __forceinline__ unsigned short bf16rn(float f, float& fh) {
  uint32_t u = __float_as_uint(f);
  uint32_t r = (u + 0x7FFFu + ((u >> 16) & 1u)) >> 16;
  fh = __uint_as_float(r << 16);
  return (unsigned short)r;
}
__device__ __forceinline__ float2 unpack2(uint32_t u) {
  return make_float2(__uint_as_float(u << 16),
                     __uint_as_float(u & 0xffff0000u));
}

__device__ __forceinline__ void gload_lds16(const void* g, void* s) {
  __builtin_amdgcn_global_load_lds(
      (const __attribute__((address_space(1))) uint32_t*)g,
      (__attribute__((address_space(3))) uint32_t*)s, 16, 0, 0);
}

// ---------------------------------------------------------------------------
// K0: per-column adjacency lists (ascending m, ballot compaction).
__global__ __launch_bounds__(64) void k_collist(const float* __restrict__ adj,
                                                int* __restrict__ col_idx,
                                                int* __restrict__ col_cnt) {
  const int n = blockIdx.x;
  const int lane = threadIdx.x;
  int cnt = 0;
  for (int m0 = 0; m0 < NN; m0 += 64) {
    const int m = m0 + lane;
    const float a = adj[(size_t)m * NN + n];
    unsigned long long mask = __ballot(a != 0.0f);
    const int prefix = __popcll(mask & ((1ull << lane) - 1ull));
    if (a != 0.0f && cnt + prefix < MAXC) col_idx[n * MAXC + cnt + prefix] = m;
    cnt += __popcll(mask);
  }
  if (lane == 0) col_cnt[n] = (cnt > MAXC) ? MAXC : cnt;
}

// K0b: packed W sub-blocks + per-block prefix scan.
// Wsub[off[n] + ji*c + mi] = W[lsh[mi]][lsh[ji]],  off[n] = sum_{i<n} cnt[i]^2
__global__ __launch_bounds__(64) void k_wsub(const float* __restrict__ W,
                                             const int* __restrict__ col_idx,
                                             const int* __restrict__ col_cnt,
                                             int* __restrict__ col_off,
                                             float* __restrict__ Wsub) {
  const int n = blockIdx.x;
  const int lane = threadIdx.x;
  __shared__ int lsh[MAXC];
  int pre = 0;
#pragma unroll
  for (int i0 = 0; i0 < NN; i0 += 64) {
    const int i = i0 + lane;
    const int cc = col_cnt[i];
    pre += (i < n) ? cc * cc : 0;
  }
#pragma unroll
  for (int off = 32; off; off >>= 1) pre += __shfl_xor(pre, off);
  if (lane == 0) col_off[n] = pre;

  const int c = col_cnt[n];
  if (lane < c) lsh[lane] = col_idx[n * MAXC + lane];
  __syncthreads();
  if (lane < c) {
    const float* Wm = W + (size_t)lsh[lane] * NN;
    float* dst = Wsub + pre + lane;
    for (int ji = 0; ji < c; ji++) dst[(size_t)ji * c] = Wm[lsh[ji]];
  }
}

// ---------------------------------------------------------------------------
// K1: fused x-prep: x (B,S,N) f32 -> xp (B*S,1024) bf16 hi|lo, xt (B,N,S) bf16,
//     plus zero-fill of the Att output region.
__global__ __launch_bounds__(256) void k_xprep(const float* __restrict__ x,
                                               unsigned short* __restrict__ xp,
                                               unsigned short* __restrict__ xt,
                                               float* __restrict__ Att) {
  __shared__ float tile[32][33];
  const int b = blockIdx.z;
  const int s0 = blockIdx.x * 32, n0 = blockIdx.y * 32;
  const float* xb = x + (size_t)b * SS * NN;
  const int tx = threadIdx.x, ty = threadIdx.y;  // (32,8)
  float fh;
#pragma unroll
  for (int i = ty; i < 32; i += 8) {
    const float v = xb[(size_t)(s0 + i) * NN + n0 + tx];
    tile[i][tx] = v;
    const unsigned short h = bf16rn(v, fh);
    const unsigned short l = bf16rn(v - fh, fh);
    unsigned short* row = xp + (size_t)(b * SS + s0 + i) * 1024 + n0 + tx;
    row[0] = h;
    row[512] = l;
  }
  {
    const int bid = (blockIdx.z * 16 + blockIdx.y) * 8 + blockIdx.x;
    const int t = ty * 32 + tx;
    f32x4* dst = (f32x4*)(Att + (size_t)bid * 2048);
    const f32x4 z = (f32x4)0.0f;
    dst[t] = z;
    dst[t + 256] = z;
  }
  __syncthreads();
  unsigned short* xtb = xt + (size_t)b * NN * SS;
#pragma unroll
  for (int i = ty; i < 32; i += 8)
    xtb[(size_t)(n0 + i) * SS + s0 + tx] = bf16rn(tile[tx][i], fh);
}

// K1b: weight splits (both Wq and Wk)
__global__ __launch_bounds__(128) void k_wsplit(const float* __restrict__ Wq,
                                                const float* __restrict__ Wk,
                                                unsigned short* __restrict__ Wqp,
                                                unsigned short* __restrict__ Wkp) {
  const int n = blockIdx.x;
  const float* src = blockIdx.y ? Wk : Wq;
  unsigned short* dst = blockIdx.y ? Wkp : Wqp;
  const int k = threadIdx.x * 4;
  float4 v = *(const float4*)(src + (size_t)n * NN + k);
  float vv[4] = {v.x, v.y, v.z, v.w};
  ushort4 h, l;
  float fh;
  h.x = bf16rn(vv[0], fh); l.x = bf16rn(vv[0] - fh, fh);
  h.y = bf16rn(vv[1], fh); l.y = bf16rn(vv[1] - fh, fh);
  h.z = bf16rn(vv[2], fh); l.z = bf16rn(vv[2] - fh, fh);
  h.w = bf16rn(vv[3], fh); l.w = bf16rn(vv[3] - fh, fh);
  *(ushort4*)(dst + (size_t)n * 1024 + k) = h;
  *(ushort4*)(dst + (size_t)n * 1024 + 512 + k) = l;
}

// ---------------------------------------------------------------------------
// K3: BOTH Linears in one block (shared X staging), 2-phase prefetch pipeline.
// Q written as packed bf16 hi|lo (split precision, error ~2^-17 downstream),
// K written bf16 (keeps the k_fused hot set L2-resident).
__global__ __launch_bounds__(256, 2) void k_lin2(const unsigned short* __restrict__ Wqp,
                                                 const unsigned short* __restrict__ Wkp,
                                                 const float* __restrict__ bq,
                                                 const float* __restrict__ bk,
                                                 const unsigned short* __restrict__ xp,
                                                 unsigned short* __restrict__ Qt,
                                                 unsigned short* __restrict__ Kt) {
  __shared__ __align__(16) char sm[49152];
  const int t = threadIdx.x;
  const int w = t >> 6, l = t & 63;
  const int id = blockIdx.x;
  const int xcd = id & 7, sub = id >> 3;
  const int bn0 = (xcd * 16 + (sub >> 2)) * 128;  // r = b*256+s
  const int bm0 = (sub & 3) * 128;                // n

  const int swz = (((l & 3) ^ ((l >> 3) & 3))) * 16;
  const char* srcb[6];
  char* dstb[6];
  int isx[6];
#pragma unroll
  for (int i = 0; i < 6; i++) {
    const int ch = w * 6 + i;
    const int panel = ch >> 3, rowgrp = ch & 7;
    const int row = rowgrp * 16 + (l >> 2);
    const char* g0 = (panel == 0) ? (const char*)Wqp
                   : (panel == 1) ? (const char*)Wkp : (const char*)xp;
    const int gr = ((panel == 2) ? bn0 : bm0) + row;
    srcb[i] = g0 + (size_t)gr * 2048 + swz;
    dstb[i] = sm + panel * 8192 + rowgrp * 1024 + l * 16;
    isx[i] = (panel == 2) ? 1 : 0;
  }

  const int fr = l & 15, fg = l >> 4;
  const int mrow = (w >> 1) * 64, ncol = (w & 1) * 64;
  const int slot = (fg ^ ((fr >> 1) & 3)) * 16;
  int offQ[4], offK[4], offB[4];
#pragma unroll
  for (int fm = 0; fm < 4; fm++) {
    offQ[fm] = (mrow + fm * 16 + fr) * 64 + slot;
    offK[fm] = 8192 + (mrow + fm * 16 + fr) * 64 + slot;
    offB[fm] = 16384 + (ncol + fm * 16 + fr) * 64 + slot;
  }

  f32x4 accq[4][4], acck[4][4];
#pragma unroll
  for (int i = 0; i < 4; i++)
#pragma unroll
    for (int j = 0; j < 4; j++) { accq[i][j] = (f32x4)0.0f; acck[i][j] = (f32x4)0.0f; }

#pragma unroll
  for (int i = 0; i < 6; i++) gload_lds16(srcb[i], dstb[i]);
  __syncthreads();

  int cur = 0;
  for (int kk = 0; kk < 48; kk++) {
    if (kk + 1 < 48) {
      const int term = (kk + 1) >> 4, k32 = (kk + 1) & 15;
      const int ka = ((term == 2) ? 1024 : 0) + k32 * 64;  // W: lo on term 2
      const int kb = ((term == 1) ? 1024 : 0) + k32 * 64;  // X: lo on term 1
      const int boff = (cur ^ 1) * 24576;
#pragma unroll
      for (int i = 0; i < 6; i++)
        gload_lds16(srcb[i] + (isx[i] ? kb : ka), dstb[i] + boff);
    }
    const char* base = sm + cur * 24576;
    bf16x8 afq[4], afk[4];
#pragma unroll
    for (int fm = 0; fm < 4; fm++) {
      afq[fm] = *(const bf16x8*)(base + offQ[fm]);
      afk[fm] = *(const bf16x8*)(base + offK[fm]);
    }
#pragma unroll
    for (int fn = 0; fn < 4; fn++) {
      const bf16x8 bv = *(const bf16x8*)(base + offB[fn]);
#pragma unroll
      for (int fm = 0; fm < 4; fm++) {
        accq[fm][fn] = __builtin_amdgcn_mfma_f32_16x16x32_bf16(afq[fm], bv, accq[fm][fn], 0, 0, 0);
        acck[fm][fn] = __builtin_amdgcn_mfma_f32_16x16x32_bf16(afk[fm], bv, acck[fm][fn], 0, 0, 0);
      }
    }
    __syncthreads();
    cur ^= 1;
  }

  // epilogue: D col = lane&15 (-> r), row = (lane>>4)*4+q (-> n)
  const int b = bn0 >> 8;
  const int sbase = (bn0 & 255) + ncol;
  float fh;
#pragma unroll
  for (int fm = 0; fm < 4; fm++) {
#pragma unroll
    for (int q = 0; q < 4; q++) {
      const int n = bm0 + mrow + fm * 16 + fg * 4 + q;
      const float bvq = bq[n];
      const float bvk = bk[n];
      unsigned short* qrow = Qt + ((size_t)b * NN + n) * 512;
#pragma unroll
      for (int fn = 0; fn < 4; fn++) {
        const int s = sbase + fn * 16 + fr;
        const float qv = accq[fm][fn][q] + bvq;
        const unsigned short qh = bf16rn(qv, fh);
        const unsigned short ql = bf16rn(qv - fh, fh);
        qrow[s] = qh;
        qrow[256 + s] = ql;
        Kt[((size_t)b * NN + n) * SS + s] = bf16rn(acck[fm][fn][q] + bvk, fh);
      }
    }
  }
}

// ---------------------------------------------------------------------------
// K4: fused sparse stage — ONE WAVE per (n,b) column; 4 batches per block
// sharing {lsh, Wsub} in LDS; one __syncthreads per block.
// Step 1 runs on the MFMA pipe (idle otherwise): v = K_rows · (q_hi + q_lo),
// A-frag = 16B/lane gather of bf16 K rows, B-frag = Q broadcast.
__global__ __launch_bounds__(256) void k_fused(const unsigned short* __restrict__ Qt,
                                               const unsigned short* __restrict__ Kt,
                                               const unsigned short* __restrict__ xt,
                                               const float* __restrict__ Wsub,
                                               const float* __restrict__ pnw,
                                               const int* __restrict__ col_idx,
                                               const int* __restrict__ col_cnt,
                                               const int* __restrict__ col_off,
                                               float* __restrict__ Att,
                                               float* __restrict__ agg) {
  // XCD-exclusive swizzle: xcd = id&7 owns batches [xcd*8, xcd*8+8).
  const int id = blockIdx.x;          // 0..8191
  const int xcd = id & 7;
  const int r = id >> 3;              // 0..1023
  const int n = r & 511;
  const int bgrp = r >> 9;            // 0..1
  const int t = threadIdx.x;
  const int wave = t >> 6, lane = t & 63;
  const int b = (xcd << 3) + (bgrp << 2) + wave;

  __shared__ int   lsh[MAXC + 1];
  __shared__ float Wsh[MAXC * MAXC];
  __shared__ float vsh[4][MAXC];
  __shared__ float ash[4][MAXC + 1];

  const int c = col_cnt[n];
  if (t <= MAXC) {                    // pad [c..MAXC] with n (diag row at c)
    int v = n;
    if (t < c) v = col_idx[n * MAXC + t];
    lsh[t] = v;
  }
  {
    const int cc = c * c;
    const float* Wp = Wsub + col_off[n];
    for (int i = t; i < cc; i += 256) Wsh[i] = Wp[i];
  }
  __syncthreads();   // the only block barrier

  // Step 1 (MFMA): vsh[ji] = <K[b,lsh[ji],:], Q[b,n,:]> for ji in [0,64).
  // A lane map: row = lane&15 (+16*rt), k = ks*32 + (lane>>4)*8 + e.
  // B = Q broadcast (same for all 16 output cols); hi+lo split accumulate.
  const int fr = lane & 15, fg = lane >> 4;
  const unsigned short* Kb = Kt + (size_t)b * NN * SS;
  const unsigned short* Qp = Qt + ((size_t)b * NN + n) * 512;  // 256 hi | 256 lo
  const unsigned short* arow[4];
#pragma unroll
  for (int rt = 0; rt < 4; rt++)
    arow[rt] = Kb + (size_t)lsh[rt * 16 + fr] * SS;
  f32x4 vacc[4];
#pragma unroll
  for (int rt = 0; rt < 4; rt++) vacc[rt] = (f32x4)0.0f;
#pragma unroll
  for (int ks = 0; ks < 8; ks++) {
    const int off = ks * 32 + fg * 8;
    const bf16x8 qh = *(const bf16x8*)(Qp + off);
    const bf16x8 ql = *(const bf16x8*)(Qp + 256 + off);
#pragma unroll
    for (int rt = 0; rt < 4; rt++) {
      const bf16x8 av = *(const bf16x8*)(arow[rt] + off);
      vacc[rt] = __builtin_amdgcn_mfma_f32_16x16x32_bf16(av, qh, vacc[rt], 0, 0, 0);
      vacc[rt] = __builtin_amdgcn_mfma_f32_16x16x32_bf16(av, ql, vacc[rt], 0, 0, 0);
    }
  }
  // D[row, col] identical across cols; lanes fr==0 publish rows fg*4+e (+16rt).
  if (fr == 0) {
#pragma unroll
    for (int rt = 0; rt < 4; rt++)
#pragma unroll
      for (int e = 0; e < 4; e++)
        vsh[wave][rt * 16 + fg * 4 + e] = vacc[rt][e];
  }
  // same-wave LDS: in-order DS pipe, no barrier needed.

  // Step 2: aval[mi] = sum_ji Wsh[ji*c+mi] * v[ji]  (lane = mi)
  float aval = 0.0f;
  if (lane < c) {
    for (int ji = 0; ji < c; ji++)
      aval += Wsh[ji * c + lane] * vsh[wave][ji];
  }

  // Step 3: in-wave softmax over {aval[0..c), pnw[n] at diag, 512-c-1 zeros}
  const float dlg = pnw[n];
  float mval = (lane < c) ? aval : -INFINITY;
#pragma unroll
  for (int off = 32; off; off >>= 1) mval = fmaxf(mval, __shfl_xor(mval, off));
  const float colmax = fmaxf(mval, fmaxf(dlg, 0.0f));
  const float e = (lane < c) ? __expf(aval - colmax) : 0.0f;
  float sum = e;
#pragma unroll
  for (int off = 32; off; off >>= 1) sum += __shfl_xor(sum, off);
  const float denom = sum + __expf(dlg - colmax)
                    + (float)(NN - c - 1) * __expf(-colmax);
  const float inv = 1.0f / denom;

  // Step 4/5: Att column scatter (rest of column stays zero-filled)
  float* Acol = Att + (size_t)b * NN * NN + n;
  if (lane < c) {
    const float attv = e * inv;
    ash[wave][lane] = attv;
    Acol[(size_t)lsh[lane] * NN] = attv;
  }
  if (lane == c) {
    const float dv = __expf(dlg - colmax) * inv;
    ash[wave][c] = dv;
    Acol[(size_t)n * NN] = dv;
  }

  // Step 6: agg[b,n,:] = sum_{mi<=c} ash[mi] * xt[b,lsh[mi],:]
  // two independent accumulator chains -> 2 outstanding gathers.
  const unsigned short* xtb = xt + (size_t)b * NN * SS;
  f32x4 acc0 = (f32x4)0.0f, acc1 = (f32x4)0.0f;
  int mi = 0;
  for (; mi + 1 <= c; mi += 2) {
    const float a0 = ash[wave][mi];
    const float a1 = ash[wave][mi + 1];
    const uint2 v0 = *(const uint2*)(xtb + (size_t)lsh[mi] * SS + lane * 4);
    const uint2 v1 = *(const uint2*)(xtb + (size_t)lsh[mi + 1] * SS + lane * 4);
    acc0.x += a0 * __uint_as_float(v0.x << 16);
    acc0.y += a0 * __uint_as_float(v0.x & 0xffff0000u);
    acc0.z += a0 * __uint_as_float(v0.y << 16);
    acc0.w += a0 * __uint_as_float(v0.y & 0xffff0000u);
    acc1.x += a1 * __uint_as_float(v1.x << 16);
    acc1.y += a1 * __uint_as_float(v1.x & 0xffff0000u);
    acc1.z += a1 * __uint_as_float(v1.y << 16);
    acc1.w += a1 * __uint_as_float(v1.y & 0xffff0000u);
  }
  if (mi <= c) {
    const float a0 = ash[wave][mi];
    const uint2 v0 = *(const uint2*)(xtb + (size_t)lsh[mi] * SS + lane * 4);
    acc0.x += a0 * __uint_as_float(v0.x << 16);
    acc0.y += a0 * __uint_as_float(v0.x & 0xffff0000u);
    acc0.z += a0 * __uint_as_float(v0.y << 16);
    acc0.w += a0 * __uint_as_float(v0.y & 0xffff0000u);
  }
  f32x4 acc;
  acc.x = acc0.x + acc1.x;
  acc.y = acc0.y + acc1.y;
  acc.z = acc0.z + acc1.z;
  acc.w = acc0.w + acc1.w;
  *(f32x4*)(agg + ((size_t)b * NN + n) * SS + lane * 4) = acc;
}

// ---------------------------------------------------------------------------
extern "C" void kernel_launch(void* const* d_in, const int* in_sizes, int n_in,
                              void* d_out, int out_size, void* d_ws, size_t ws_size,
                              hipStream_t stream) {
  const float* x    = (const float*)d_in[0];
  const float* adj  = (const float*)d_in[1];
  const float* W    = (const float*)d_in[2];
  const float* pnw  = (const float*)d_in[3];
  const float* Wq_w = (const float*)d_in[4];
  const float* Wq_b = (const float*)d_in[5];
  const float* Wk_w = (const float*)d_in[6];
  const float* Wk_b = (const float*)d_in[7];

  float* agg = (float*)d_out;                        // (B,N,S)
  float* Att = (float*)d_out + (size_t)BB * NN * SS; // (B,N,N)

  char* p = (char*)d_ws;
  unsigned short* xp  = (unsigned short*)p; p += (size_t)BB * SS * 1024 * 2;  // 33.55 MB
  unsigned short* Wqp = (unsigned short*)p; p += (size_t)NN * 1024 * 2;       // 1.05 MB
  unsigned short* Wkp = (unsigned short*)p; p += (size_t)NN * 1024 * 2;       // 1.05 MB
  unsigned short* Qt  = (unsigned short*)p; p += (size_t)BB * NN * 512 * 2;   // 33.55 MB (hi|lo)
  unsigned short* Kt  = (unsigned short*)p; p += (size_t)BB * NN * SS * 2;    // 16.78 MB
  unsigned short* xt  = (unsigned short*)p; p += (size_t)BB * NN * SS * 2;    // 16.78 MB
  float* Wsub = (float*)p; p += (size_t)NN * MAXC * MAXC * 4;                 // 8.39 MB (bound)
  int* col_idx = (int*)p; p += (size_t)NN * MAXC * 4;
  int* col_cnt = (int*)p; p += NN * 4;
  int* col_off = (int*)p;

  k_collist<<<dim3(NN), dim3(64), 0, stream>>>(adj, col_idx, col_cnt);
  k_wsub<<<dim3(NN), dim3(64), 0, stream>>>(W, col_idx, col_cnt, col_off, Wsub);
  k_xprep<<<dim3(SS / 32, NN / 32, BB), dim3(32, 8), 0, stream>>>(x, xp, xt, Att);
  k_wsplit<<<dim3(NN, 2), dim3(128), 0, stream>>>(Wq_w, Wk_w, Wqp, Wkp);

  k_lin2<<<dim3(512), dim3(256), 0, stream>>>(Wqp, Wkp, Wq_b, Wk_b, xp, Qt, Kt);
  k_fused<<<dim3(8192), dim3(256), 0, stream>>>(Qt, Kt, xt, Wsub, pnw,
                                                col_idx, col_cnt, col_off,
                                                Att, agg);
}

// Round 12
// 164.598 us; speedup vs baseline: 1.2511x; 1.2511x over previous
//
#include <hip/hip_runtime.h>
#include <cstdint>
#include <cmath>

#define BB 64
#define SS 256
#define NN 512
#define MAXC 64   // max nonzeros per adj column (mean ~25.6, true max ~46)

typedef float f32x4 __attribute__((ext_vector_type(4)));
typedef short bf16x8 __attribute__((ext_vector_type(8)));

__device__ __forceinline__ unsigned short bf16rn(float f, float& fh) {
  uint32_t u = __float_as_uint(f);
  uint32_t r = (u + 0x7FFFu + ((u >> 16) & 1u)) >> 16;
  fh = __uint_as_float(r << 16);
  return (unsigned short)r;
}
__device__ __forceinline__ float2 unpack2(uint32_t u) {
  return make_float2(__uint_as_float(u << 16),
                     __uint_as_float(u & 0xffff0000u));
}

__device__ __forceinline__ void gload_lds16(const void* g, void* s) {
  __builtin_amdgcn_global_load_lds(
      (const __attribute__((address_space(1))) uint32_t*)g,
      (__attribute__((address_space(3))) uint32_t*)s, 16, 0, 0);
}

// ---------------------------------------------------------------------------
// K0: per-column adjacency lists (ascending m, ballot compaction).
__global__ __launch_bounds__(64) void k_collist(const float* __restrict__ adj,
                                                int* __restrict__ col_idx,
                                                int* __restrict__ col_cnt) {
  const int n = blockIdx.x;
  const int lane = threadIdx.x;
  int cnt = 0;
  for (int m0 = 0; m0 < NN; m0 += 64) {
    const int m = m0 + lane;
    const float a = adj[(size_t)m * NN + n];
    unsigned long long mask = __ballot(a != 0.0f);
    const int prefix = __popcll(mask & ((1ull << lane) - 1ull));
    if (a != 0.0f && cnt + prefix < MAXC) col_idx[n * MAXC + cnt + prefix] = m;
    cnt += __popcll(mask);
  }
  if (lane == 0) col_cnt[n] = (cnt > MAXC) ? MAXC : cnt;
}

// K0b: packed W sub-blocks + per-block prefix scan.
// Wsub[off[n] + ji*c + mi] = W[lsh[mi]][lsh[ji]],  off[n] = sum_{i<n} cnt[i]^2
__global__ __launch_bounds__(64) void k_wsub(const float* __restrict__ W,
                                             const int* __restrict__ col_idx,
                                             const int* __restrict__ col_cnt,
                                             int* __restrict__ col_off,
                                             float* __restrict__ Wsub) {
  const int n = blockIdx.x;
  const int lane = threadIdx.x;
  __shared__ int lsh[MAXC];
  int pre = 0;
#pragma unroll
  for (int i0 = 0; i0 < NN; i0 += 64) {
    const int i = i0 + lane;
    const int cc = col_cnt[i];
    pre += (i < n) ? cc * cc : 0;
  }
#pragma unroll
  for (int off = 32; off; off >>= 1) pre += __shfl_xor(pre, off);
  if (lane == 0) col_off[n] = pre;

  const int c = col_cnt[n];
  if (lane < c) lsh[lane] = col_idx[n * MAXC + lane];
  __syncthreads();
  if (lane < c) {
    const float* Wm = W + (size_t)lsh[lane] * NN;
    float* dst = Wsub + pre + lane;
    for (int ji = 0; ji < c; ji++) dst[(size_t)ji * c] = Wm[lsh[ji]];
  }
}

// ---------------------------------------------------------------------------
// K1: fused x-prep: x (B,S,N) f32 -> xp (B*S,1024) bf16 hi|lo, xt (B,N,S) bf16,
//     plus zero-fill of the Att output region.
__global__ __launch_bounds__(256) void k_xprep(const float* __restrict__ x,
                                               unsigned short* __restrict__ xp,
                                               unsigned short* __restrict__ xt,
                                               float* __restrict__ Att) {
  __shared__ float tile[32][33];
  const int b = blockIdx.z;
  const int s0 = blockIdx.x * 32, n0 = blockIdx.y * 32;
  const float* xb = x + (size_t)b * SS * NN;
  const int tx = threadIdx.x, ty = threadIdx.y;  // (32,8)
  float fh;
#pragma unroll
  for (int i = ty; i < 32; i += 8) {
    const float v = xb[(size_t)(s0 + i) * NN + n0 + tx];
    tile[i][tx] = v;
    const unsigned short h = bf16rn(v, fh);
    const unsigned short l = bf16rn(v - fh, fh);
    unsigned short* row = xp + (size_t)(b * SS + s0 + i) * 1024 + n0 + tx;
    row[0] = h;
    row[512] = l;
  }
  {
    const int bid = (blockIdx.z * 16 + blockIdx.y) * 8 + blockIdx.x;
    const int t = ty * 32 + tx;
    f32x4* dst = (f32x4*)(Att + (size_t)bid * 2048);
    const f32x4 z = (f32x4)0.0f;
    dst[t] = z;
    dst[t + 256] = z;
  }
  __syncthreads();
  unsigned short* xtb = xt + (size_t)b * NN * SS;
#pragma unroll
  for (int i = ty; i < 32; i += 8)
    xtb[(size_t)(n0 + i) * SS + s0 + tx] = bf16rn(tile[tx][i], fh);
}

// K1b: weight splits (both Wq and Wk)
__global__ __launch_bounds__(128) void k_wsplit(const float* __restrict__ Wq,
                                                const float* __restrict__ Wk,
                                                unsigned short* __restrict__ Wqp,
                                                unsigned short* __restrict__ Wkp) {
  const int n = blockIdx.x;
  const float* src = blockIdx.y ? Wk : Wq;
  unsigned short* dst = blockIdx.y ? Wkp : Wqp;
  const int k = threadIdx.x * 4;
  float4 v = *(const float4*)(src + (size_t)n * NN + k);
  float vv[4] = {v.x, v.y, v.z, v.w};
  ushort4 h, l;
  float fh;
  h.x = bf16rn(vv[0], fh); l.x = bf16rn(vv[0] - fh, fh);
  h.y = bf16rn(vv[1], fh); l.y = bf16rn(vv[1] - fh, fh);
  h.z = bf16rn(vv[2], fh); l.z = bf16rn(vv[2] - fh, fh);
  h.w = bf16rn(vv[3], fh); l.w = bf16rn(vv[3] - fh, fh);
  *(ushort4*)(dst + (size_t)n * 1024 + k) = h;
  *(ushort4*)(dst + (size_t)n * 1024 + 512 + k) = l;
}

// ---------------------------------------------------------------------------
// K3: BOTH Linears in one block (shared X staging), 2-phase prefetch pipeline.
// Q written f32 (read once downstream -> accuracy), K written bf16 (hot set).
__global__ __launch_bounds__(256, 2) void k_lin2(const unsigned short* __restrict__ Wqp,
                                                 const unsigned short* __restrict__ Wkp,
                                                 const float* __restrict__ bq,
                                                 const float* __restrict__ bk,
                                                 const unsigned short* __restrict__ xp,
                                                 float* __restrict__ Qt,
                                                 unsigned short* __restrict__ Kt) {
  __shared__ __align__(16) char sm[49152];
  const int t = threadIdx.x;
  const int w = t >> 6, l = t & 63;
  const int id = blockIdx.x;
  const int xcd = id & 7, sub = id >> 3;
  const int bn0 = (xcd * 16 + (sub >> 2)) * 128;  // r = b*256+s
  const int bm0 = (sub & 3) * 128;                // n

  const int swz = (((l & 3) ^ ((l >> 3) & 3))) * 16;
  const char* srcb[6];
  char* dstb[6];
  int isx[6];
#pragma unroll
  for (int i = 0; i < 6; i++) {
    const int ch = w * 6 + i;
    const int panel = ch >> 3, rowgrp = ch & 7;
    const int row = rowgrp * 16 + (l >> 2);
    const char* g0 = (panel == 0) ? (const char*)Wqp
                   : (panel == 1) ? (const char*)Wkp : (const char*)xp;
    const int gr = ((panel == 2) ? bn0 : bm0) + row;
    srcb[i] = g0 + (size_t)gr * 2048 + swz;
    dstb[i] = sm + panel * 8192 + rowgrp * 1024 + l * 16;
    isx[i] = (panel == 2) ? 1 : 0;
  }

  const int fr = l & 15, fg = l >> 4;
  const int mrow = (w >> 1) * 64, ncol = (w & 1) * 64;
  const int slot = (fg ^ ((fr >> 1) & 3)) * 16;
  int offQ[4], offK[4], offB[4];
#pragma unroll
  for (int fm = 0; fm < 4; fm++) {
    offQ[fm] = (mrow + fm * 16 + fr) * 64 + slot;
    offK[fm] = 8192 + (mrow + fm * 16 + fr) * 64 + slot;
    offB[fm] = 16384 + (ncol + fm * 16 + fr) * 64 + slot;
  }

  f32x4 accq[4][4], acck[4][4];
#pragma unroll
  for (int i = 0; i < 4; i++)
#pragma unroll
    for (int j = 0; j < 4; j++) { accq[i][j] = (f32x4)0.0f; acck[i][j] = (f32x4)0.0f; }

#pragma unroll
  for (int i = 0; i < 6; i++) gload_lds16(srcb[i], dstb[i]);
  __syncthreads();

  int cur = 0;
  for (int kk = 0; kk < 48; kk++) {
    if (kk + 1 < 48) {
      const int term = (kk + 1) >> 4, k32 = (kk + 1) & 15;
      const int ka = ((term == 2) ? 1024 : 0) + k32 * 64;  // W: lo on term 2
      const int kb = ((term == 1) ? 1024 : 0) + k32 * 64;  // X: lo on term 1
      const int boff = (cur ^ 1) * 24576;
#pragma unroll
      for (int i = 0; i < 6; i++)
        gload_lds16(srcb[i] + (isx[i] ? kb : ka), dstb[i] + boff);
    }
    const char* base = sm + cur * 24576;
    bf16x8 afq[4], afk[4];
#pragma unroll
    for (int fm = 0; fm < 4; fm++) {
      afq[fm] = *(const bf16x8*)(base + offQ[fm]);
      afk[fm] = *(const bf16x8*)(base + offK[fm]);
    }
#pragma unroll
    for (int fn = 0; fn < 4; fn++) {
      const bf16x8 bv = *(const bf16x8*)(base + offB[fn]);
#pragma unroll
      for (int fm = 0; fm < 4; fm++) {
        accq[fm][fn] = __builtin_amdgcn_mfma_f32_16x16x32_bf16(afq[fm], bv, accq[fm][fn], 0, 0, 0);
        acck[fm][fn] = __builtin_amdgcn_mfma_f32_16x16x32_bf16(afk[fm], bv, acck[fm][fn], 0, 0, 0);
      }
    }
    __syncthreads();
    cur ^= 1;
  }

  // epilogue: D col = lane&15 (-> r), row = (lane>>4)*4+q (-> n)
  const int b = bn0 >> 8;
  const int sbase = (bn0 & 255) + ncol;
  float fh;
#pragma unroll
  for (int fm = 0; fm < 4; fm++) {
#pragma unroll
    for (int q = 0; q < 4; q++) {
      const int n = bm0 + mrow + fm * 16 + fg * 4 + q;
      const float bvq = bq[n];
      const float bvk = bk[n];
#pragma unroll
      for (int fn = 0; fn < 4; fn++) {
        const int s = sbase + fn * 16 + fr;
        Qt[((size_t)b * NN + n) * SS + s] = accq[fm][fn][q] + bvq;
        Kt[((size_t)b * NN + n) * SS + s] = bf16rn(acck[fm][fn][q] + bvk, fh);
      }
    }
  }
}

// ---------------------------------------------------------------------------
// K4: fused sparse stage — ONE WAVE per (n,b) column; 8 batches per block
// (8 waves, 512 thr) sharing {lsh, lshB, Wsh} in LDS; one __syncthreads.
// K bf16 + xt bf16 (L2 hot set), Q f32 (accuracy, read once).
// lshB = row byte offsets precomputed (kills per-access v_mul in gathers).
__global__ __launch_bounds__(512) void k_fused(const float* __restrict__ Qt,
                                               const unsigned short* __restrict__ Kt,
                                               const unsigned short* __restrict__ xt,
                                               const float* __restrict__ Wsub,
                                               const float* __restrict__ pnw,
                                               const int* __restrict__ col_idx,
                                               const int* __restrict__ col_cnt,
                                               const int* __restrict__ col_off,
                                               float* __restrict__ Att,
                                               float* __restrict__ agg) {
  // XCD-exclusive swizzle: xcd = id&7 owns batches [xcd*8, xcd*8+8);
  // 8 waves cover those 8 batches for one column n = id>>3.
  const int id = blockIdx.x;          // 0..4095
  const int xcd = id & 7;
  const int n = id >> 3;              // 0..511
  const int t = threadIdx.x;
  const int wave = t >> 6, lane = t & 63;
  const int b = (xcd << 3) + wave;

  __shared__ int   lsh[MAXC + 1];
  __shared__ int   lshB[MAXC + 1];    // lsh * 512 (byte offset, 256 bf16 rows)
  __shared__ float Wsh[MAXC * MAXC];
  __shared__ float vsh[8][MAXC];
  __shared__ float ash[8][MAXC + 1];

  const int c = col_cnt[n];
  if (t < c) {
    const int v = col_idx[n * MAXC + t];
    lsh[t] = v;
    lshB[t] = v << 9;
  }
  if (t == c) { lsh[c] = n; lshB[c] = n << 9; }
  {
    const int cc = c * c;
    const float* Wp = Wsub + col_off[n];
    for (int i = t; i < cc; i += 512) Wsh[i] = Wp[i];
  }
  __syncthreads();   // the only block barrier

  // Step 1: v[ji] = <K[b,lsh[ji],:], Q[b,n,:]>; 16 lanes/dot, 4 dots in flight.
  const int g = lane >> 4, q = lane & 15;
  const float* Qrow = Qt + ((size_t)b * NN + n) * SS;
  const char* Kb = (const char*)(Kt + (size_t)b * NN * SS);
  f32x4 qreg[4];
#pragma unroll
  for (int u = 0; u < 4; u++)
    qreg[u] = *(const f32x4*)(Qrow + (u * 16 + q) * 4);
  for (int j0 = 0; j0 < c; j0 += 4) {
    const int ji = j0 + g;
    float p = 0.0f;
    if (ji < c) {
      const char* Krow = Kb + lshB[ji];
#pragma unroll
      for (int u = 0; u < 4; u++) {
        const uint2 kv = *(const uint2*)(Krow + u * 128 + q * 8);
        const float2 k01 = unpack2(kv.x);
        const float2 k23 = unpack2(kv.y);
        p += k01.x * qreg[u].x + k01.y * qreg[u].y + k23.x * qreg[u].z + k23.y * qreg[u].w;
      }
    }
    p += __shfl_down(p, 8, 16);
    p += __shfl_down(p, 4, 16);
    p += __shfl_down(p, 2, 16);
    p += __shfl_down(p, 1, 16);
    if (q == 0 && ji < c) vsh[wave][ji] = p;
  }
  // same-wave LDS: in-order DS pipe, no barrier needed.

  // Step 2: aval[mi] = sum_ji Wsh[ji*c+mi] * v[ji]  (lane = mi)
  float aval = 0.0f;
  if (lane < c) {
    for (int ji = 0; ji < c; ji++)
      aval += Wsh[ji * c + lane] * vsh[wave][ji];
  }

  // Step 3: in-wave softmax over {aval[0..c), pnw[n] at diag, 512-c-1 zeros}
  const float dlg = pnw[n];
  float mval = (lane < c) ? aval : -INFINITY;
#pragma unroll
  for (int off = 32; off; off >>= 1) mval = fmaxf(mval, __shfl_xor(mval, off));
  const float colmax = fmaxf(mval, fmaxf(dlg, 0.0f));
  const float e = (lane < c) ? __expf(aval - colmax) : 0.0f;
  float sum = e;
#pragma unroll
  for (int off = 32; off; off >>= 1) sum += __shfl_xor(sum, off);
  const float denom = sum + __expf(dlg - colmax)
                    + (float)(NN - c - 1) * __expf(-colmax);
  const float inv = 1.0f / denom;

  // Step 4/5: Att column scatter (rest of column stays zero-filled)
  float* Acol = Att + (size_t)b * NN * NN + n;
  if (lane < c) {
    const float attv = e * inv;
    ash[wave][lane] = attv;
    Acol[(size_t)lsh[lane] * NN] = attv;
  }
  if (lane == c) {
    const float dv = __expf(dlg - colmax) * inv;
    ash[wave][c] = dv;
    Acol[(size_t)n * NN] = dv;
  }

  // Step 6: agg[b,n,:] = sum_{mi<=c} ash[mi] * xt[b,lsh[mi],:]
  const char* xtb = (const char*)(xt + (size_t)b * NN * SS);
  f32x4 acc = (f32x4)0.0f;
  for (int mi = 0; mi <= c; mi++) {
    const float a = ash[wave][mi];
    const uint2 v = *(const uint2*)(xtb + lshB[mi] + lane * 8);
    acc.x += a * __uint_as_float(v.x << 16);
    acc.y += a * __uint_as_float(v.x & 0xffff0000u);
    acc.z += a * __uint_as_float(v.y << 16);
    acc.w += a * __uint_as_float(v.y & 0xffff0000u);
  }
  *(f32x4*)(agg + ((size_t)b * NN + n) * SS + lane * 4) = acc;
}

// ---------------------------------------------------------------------------
extern "C" void kernel_launch(void* const* d_in, const int* in_sizes, int n_in,
                              void* d_out, int out_size, void* d_ws, size_t ws_size,
                              hipStream_t stream) {
  const float* x    = (const float*)d_in[0];
  const float* adj  = (const float*)d_in[1];
  const float* W    = (const float*)d_in[2];
  const float* pnw  = (const float*)d_in[3];
  const float* Wq_w = (const float*)d_in[4];
  const float* Wq_b = (const float*)d_in[5];
  const float* Wk_w = (const float*)d_in[6];
  const float* Wk_b = (const float*)d_in[7];

  float* agg = (float*)d_out;                        // (B,N,S)
  float* Att = (float*)d_out + (size_t)BB * NN * SS; // (B,N,N)

  char* p = (char*)d_ws;
  unsigned short* xp  = (unsigned short*)p; p += (size_t)BB * SS * 1024 * 2;  // 33.55 MB
  unsigned short* Wqp = (unsigned short*)p; p += (size_t)NN * 1024 * 2;       // 1.05 MB
  unsigned short* Wkp = (unsigned short*)p; p += (size_t)NN * 1024 * 2;       // 1.05 MB
  float* Qt  = (float*)p; p += (size_t)BB * NN * SS * 4;                      // 33.55 MB (f32)
  unsigned short* Kt  = (unsigned short*)p; p += (size_t)BB * NN * SS * 2;    // 16.78 MB
  unsigned short* xt  = (unsigned short*)p; p += (size_t)BB * NN * SS * 2;    // 16.78 MB
  float* Wsub = (float*)p; p += (size_t)NN * MAXC * MAXC * 4;                 // 8.39 MB (bound)
  int* col_idx = (int*)p; p += (size_t)NN * MAXC * 4;
  int* col_cnt = (int*)p; p += NN * 4;
  int* col_off = (int*)p;

  k_collist<<<dim3(NN), dim3(64), 0, stream>>>(adj, col_idx, col_cnt);
  k_wsub<<<dim3(NN), dim3(64), 0, stream>>>(W, col_idx, col_cnt, col_off, Wsub);
  k_xprep<<<dim3(SS / 32, NN / 32, BB), dim3(32, 8), 0, stream>>>(x, xp, xt, Att);
  k_wsplit<<<dim3(NN, 2), dim3(128), 0, stream>>>(Wq_w, Wk_w, Wqp, Wkp);

  k_lin2<<<dim3(512), dim3(256), 0, stream>>>(Wqp, Wkp, Wq_b, Wk_b, xp, Qt, Kt);
  k_fused<<<dim3(4096), dim3(512), 0, stream>>>(Qt, Kt, xt, Wsub, pnw,
                                                col_idx, col_cnt, col_off,
                                                Att, agg);
}

// Round 14
// 159.352 us; speedup vs baseline: 1.2923x; 1.0329x over previous
//
#include <hip/hip_runtime.h>
#include <cstdint>
#include <cmath>

#define BB 64
#define SS 256
#define NN 512
#define MAXC 64   // max nonzeros per adj column (mean ~25.6, true max ~46)

typedef float f32x4 __attribute__((ext_vector_type(4)));
typedef short bf16x8 __attribute__((ext_vector_type(8)));

__device__ __forceinline__ unsigned short bf16rn(float f, float& fh) {
  uint32_t u = __float_as_uint(f);
  uint32_t r = (u + 0x7FFFu + ((u >> 16) & 1u)) >> 16;
  fh = __uint_as_float(r << 16);
  return (unsigned short)r;
}
__device__ __forceinline__ float2 unpack2(uint32_t u) {
  return make_float2(__uint_as_float(u << 16),
                     __uint_as_float(u & 0xffff0000u));
}

__device__ __forceinline__ void gload_lds16(const void* g, void* s) {
  __builtin_amdgcn_global_load_lds(
      (const __attribute__((address_space(1))) uint32_t*)g,
      (__attribute__((address_space(3))) uint32_t*)s, 16, 0, 0);
}

// ---------------------------------------------------------------------------
// K0: per-column adjacency lists (ascending m, ballot compaction).
__global__ __launch_bounds__(64) void k_collist(const float* __restrict__ adj,
                                                int* __restrict__ col_idx,
                                                int* __restrict__ col_cnt) {
  const int n = blockIdx.x;
  const int lane = threadIdx.x;
  int cnt = 0;
  for (int m0 = 0; m0 < NN; m0 += 64) {
    const int m = m0 + lane;
    const float a = adj[(size_t)m * NN + n];
    unsigned long long mask = __ballot(a != 0.0f);
    const int prefix = __popcll(mask & ((1ull << lane) - 1ull));
    if (a != 0.0f && cnt + prefix < MAXC) col_idx[n * MAXC + cnt + prefix] = m;
    cnt += __popcll(mask);
  }
  if (lane == 0) col_cnt[n] = (cnt > MAXC) ? MAXC : cnt;
}

// K0b: packed W sub-blocks + per-block prefix scan.
// Wsub[off[n] + ji*c + mi] = W[lsh[mi]][lsh[ji]],  off[n] = sum_{i<n} cnt[i]^2
__global__ __launch_bounds__(64) void k_wsub(const float* __restrict__ W,
                                             const int* __restrict__ col_idx,
                                             const int* __restrict__ col_cnt,
                                             int* __restrict__ col_off,
                                             float* __restrict__ Wsub) {
  const int n = blockIdx.x;
  const int lane = threadIdx.x;
  __shared__ int lsh[MAXC];
  int pre = 0;
#pragma unroll
  for (int i0 = 0; i0 < NN; i0 += 64) {
    const int i = i0 + lane;
    const int cc = col_cnt[i];
    pre += (i < n) ? cc * cc : 0;
  }
#pragma unroll
  for (int off = 32; off; off >>= 1) pre += __shfl_xor(pre, off);
  if (lane == 0) col_off[n] = pre;

  const int c = col_cnt[n];
  if (lane < c) lsh[lane] = col_idx[n * MAXC + lane];
  __syncthreads();
  if (lane < c) {
    const float* Wm = W + (size_t)lsh[lane] * NN;
    float* dst = Wsub + pre + lane;
    for (int ji = 0; ji < c; ji++) dst[(size_t)ji * c] = Wm[lsh[ji]];
  }
}

// ---------------------------------------------------------------------------
// K1: fused x-prep: x (B,S,N) f32 -> xp (B*S,1024) bf16 hi|lo, xt (B,N,S) bf16,
//     plus zero-fill of the Att output region.
__global__ __launch_bounds__(256) void k_xprep(const float* __restrict__ x,
                                               unsigned short* __restrict__ xp,
                                               unsigned short* __restrict__ xt,
                                               float* __restrict__ Att) {
  __shared__ float tile[32][33];
  const int b = blockIdx.z;
  const int s0 = blockIdx.x * 32, n0 = blockIdx.y * 32;
  const float* xb = x + (size_t)b * SS * NN;
  const int tx = threadIdx.x, ty = threadIdx.y;  // (32,8)
  float fh;
#pragma unroll
  for (int i = ty; i < 32; i += 8) {
    const float v = xb[(size_t)(s0 + i) * NN + n0 + tx];
    tile[i][tx] = v;
    const unsigned short h = bf16rn(v, fh);
    const unsigned short l = bf16rn(v - fh, fh);
    unsigned short* row = xp + (size_t)(b * SS + s0 + i) * 1024 + n0 + tx;
    row[0] = h;
    row[512] = l;
  }
  {
    const int bid = (blockIdx.z * 16 + blockIdx.y) * 8 + blockIdx.x;
    const int t = ty * 32 + tx;
    f32x4* dst = (f32x4*)(Att + (size_t)bid * 2048);
    const f32x4 z = (f32x4)0.0f;
    dst[t] = z;
    dst[t + 256] = z;
  }
  __syncthreads();
  unsigned short* xtb = xt + (size_t)b * NN * SS;
#pragma unroll
  for (int i = ty; i < 32; i += 8)
    xtb[(size_t)(n0 + i) * SS + s0 + tx] = bf16rn(tile[tx][i], fh);
}

// K1b: weight splits (both Wq and Wk)
__global__ __launch_bounds__(128) void k_wsplit(const float* __restrict__ Wq,
                                                const float* __restrict__ Wk,
                                                unsigned short* __restrict__ Wqp,
                                                unsigned short* __restrict__ Wkp) {
  const int n = blockIdx.x;
  const float* src = blockIdx.y ? Wk : Wq;
  unsigned short* dst = blockIdx.y ? Wkp : Wqp;
  const int k = threadIdx.x * 4;
  float4 v = *(const float4*)(src + (size_t)n * NN + k);
  float vv[4] = {v.x, v.y, v.z, v.w};
  ushort4 h, l;
  float fh;
  h.x = bf16rn(vv[0], fh); l.x = bf16rn(vv[0] - fh, fh);
  h.y = bf16rn(vv[1], fh); l.y = bf16rn(vv[1] - fh, fh);
  h.z = bf16rn(vv[2], fh); l.z = bf16rn(vv[2] - fh, fh);
  h.w = bf16rn(vv[3], fh); l.w = bf16rn(vv[3] - fh, fh);
  *(ushort4*)(dst + (size_t)n * 1024 + k) = h;
  *(ushort4*)(dst + (size_t)n * 1024 + 512 + k) = l;
}

// ---------------------------------------------------------------------------
// K3: BOTH Linears in one block (shared X staging), 2-phase prefetch pipeline.
// 3-term bf16 split (hi.hi + hi.lo + lo.hi), K'=1536 -> 48 K-steps.
// Q written f32 (accuracy), K written bf16 (L2 hot set).
__global__ __launch_bounds__(256, 2) void k_lin2(const unsigned short* __restrict__ Wqp,
                                                 const unsigned short* __restrict__ Wkp,
                                                 const float* __restrict__ bq,
                                                 const float* __restrict__ bk,
                                                 const unsigned short* __restrict__ xp,
                                                 float* __restrict__ Qt,
                                                 unsigned short* __restrict__ Kt) {
  __shared__ __align__(16) char sm[49152];
  const int t = threadIdx.x;
  const int w = t >> 6, l = t & 63;
  const int id = blockIdx.x;
  const int xcd = id & 7, sub = id >> 3;
  const int bn0 = (xcd * 16 + (sub >> 2)) * 128;  // r = b*256+s
  const int bm0 = (sub & 3) * 128;                // n

  const int swz = (((l & 3) ^ ((l >> 3) & 3))) * 16;
  const char* srcb[6];
  char* dstb[6];
  int isx[6];
#pragma unroll
  for (int i = 0; i < 6; i++) {
    const int ch = w * 6 + i;
    const int panel = ch >> 3, rowgrp = ch & 7;
    const int row = rowgrp * 16 + (l >> 2);
    const char* g0 = (panel == 0) ? (const char*)Wqp
                   : (panel == 1) ? (const char*)Wkp : (const char*)xp;
    const int gr = ((panel == 2) ? bn0 : bm0) + row;
    srcb[i] = g0 + (size_t)gr * 2048 + swz;
    dstb[i] = sm + panel * 8192 + rowgrp * 1024 + l * 16;
    isx[i] = (panel == 2) ? 1 : 0;
  }

  const int fr = l & 15, fg = l >> 4;
  const int mrow = (w >> 1) * 64, ncol = (w & 1) * 64;
  const int slot = (fg ^ ((fr >> 1) & 3)) * 16;
  int offQ[4], offK[4], offB[4];
#pragma unroll
  for (int fm = 0; fm < 4; fm++) {
    offQ[fm] = (mrow + fm * 16 + fr) * 64 + slot;
    offK[fm] = 8192 + (mrow + fm * 16 + fr) * 64 + slot;
    offB[fm] = 16384 + (ncol + fm * 16 + fr) * 64 + slot;
  }

  f32x4 accq[4][4], acck[4][4];
#pragma unroll
  for (int i = 0; i < 4; i++)
#pragma unroll
    for (int j = 0; j < 4; j++) { accq[i][j] = (f32x4)0.0f; acck[i][j] = (f32x4)0.0f; }

#pragma unroll
  for (int i = 0; i < 6; i++) gload_lds16(srcb[i], dstb[i]);
  __syncthreads();

  int cur = 0;
  for (int kk = 0; kk < 48; kk++) {
    if (kk + 1 < 48) {
      const int term = (kk + 1) >> 4, k32 = (kk + 1) & 15;
      const int ka = ((term == 2) ? 1024 : 0) + k32 * 64;  // W: lo on term 2
      const int kb = ((term == 1) ? 1024 : 0) + k32 * 64;  // X: lo on term 1
      const int boff = (cur ^ 1) * 24576;
#pragma unroll
      for (int i = 0; i < 6; i++)
        gload_lds16(srcb[i] + (isx[i] ? kb : ka), dstb[i] + boff);
    }
    const char* base = sm + cur * 24576;
    bf16x8 afq[4], afk[4];
#pragma unroll
    for (int fm = 0; fm < 4; fm++) {
      afq[fm] = *(const bf16x8*)(base + offQ[fm]);
      afk[fm] = *(const bf16x8*)(base + offK[fm]);
    }
#pragma unroll
    for (int fn = 0; fn < 4; fn++) {
      const bf16x8 bv = *(const bf16x8*)(base + offB[fn]);
#pragma unroll
      for (int fm = 0; fm < 4; fm++) {
        accq[fm][fn] = __builtin_amdgcn_mfma_f32_16x16x32_bf16(afq[fm], bv, accq[fm][fn], 0, 0, 0);
        acck[fm][fn] = __builtin_amdgcn_mfma_f32_16x16x32_bf16(afk[fm], bv, acck[fm][fn], 0, 0, 0);
      }
    }
    __syncthreads();
    cur ^= 1;
  }

  // epilogue: D col = lane&15 (-> r), row = (lane>>4)*4+q (-> n)
  const int b = bn0 >> 8;
  const int sbase = (bn0 & 255) + ncol;
  float fh;
#pragma unroll
  for (int fm = 0; fm < 4; fm++) {
#pragma unroll
    for (int q = 0; q < 4; q++) {
      const int n = bm0 + mrow + fm * 16 + fg * 4 + q;
      const float bvq = bq[n];
      const float bvk = bk[n];
#pragma unroll
      for (int fn = 0; fn < 4; fn++) {
        const int s = sbase + fn * 16 + fr;
        Qt[((size_t)b * NN + n) * SS + s] = accq[fm][fn][q] + bvq;
        Kt[((size_t)b * NN + n) * SS + s] = bf16rn(acck[fm][fn][q] + bvk, fh);
      }
    }
  }
}

// ---------------------------------------------------------------------------
// K4: fused sparse stage — ONE WAVE per (n,b) column; 4 batches per block
// (keeps per-XCD hot set {4xK, 4xxt, Wsub} < 4MiB L2); one __syncthreads.
// K bf16 + xt bf16, Q f32. lshB = precomputed row byte offsets.
__global__ __launch_bounds__(256) void k_fused(const float* __restrict__ Qt,
                                               const unsigned short* __restrict__ Kt,
                                               const unsigned short* __restrict__ xt,
                                               const float* __restrict__ Wsub,
                                               const float* __restrict__ pnw,
                                               const int* __restrict__ col_idx,
                                               const int* __restrict__ col_cnt,
                                               const int* __restrict__ col_off,
                                               float* __restrict__ Att,
                                               float* __restrict__ agg) {
  // XCD-exclusive swizzle: xcd = id&7 owns batches [xcd*8, xcd*8+8).
  const int id = blockIdx.x;          // 0..8191
  const int xcd = id & 7;
  const int r = id >> 3;              // 0..1023
  const int n = r & 511;
  const int bgrp = r >> 9;            // 0..1
  const int t = threadIdx.x;
  const int wave = t >> 6, lane = t & 63;
  const int b = (xcd << 3) + (bgrp << 2) + wave;

  __shared__ int   lsh[MAXC + 1];
  __shared__ int   lshB[MAXC + 1];    // lsh * 512 (byte offset of a bf16 row)
  __shared__ float Wsh[MAXC * MAXC];
  __shared__ float vsh[4][MAXC];
  __shared__ float ash[4][MAXC + 1];

  const int c = col_cnt[n];
  if (t < c) {
    const int v = col_idx[n * MAXC + t];
    lsh[t] = v;
    lshB[t] = v << 9;
  }
  if (t == c) { lsh[c] = n; lshB[c] = n << 9; }
  {
    const int cc = c * c;
    const float* Wp = Wsub + col_off[n];
    for (int i = t; i < cc; i += 256) Wsh[i] = Wp[i];
  }
  __syncthreads();   // the only block barrier

  // Step 1: v[ji] = <K[b,lsh[ji],:], Q[b,n,:]>; 16 lanes/dot, 4 dots in flight.
  const int g = lane >> 4, q = lane & 15;
  const float* Qrow = Qt + ((size_t)b * NN + n) * SS;
  const char* Kb = (const char*)(Kt + (size_t)b * NN * SS);
  f32x4 qreg[4];
#pragma unroll
  for (int u = 0; u < 4; u++)
    qreg[u] = *(const f32x4*)(Qrow + (u * 16 + q) * 4);
  for (int j0 = 0; j0 < c; j0 += 4) {
    const int ji = j0 + g;
    float p = 0.0f;
    if (ji < c) {
      const char* Krow = Kb + lshB[ji];
#pragma unroll
      for (int u = 0; u < 4; u++) {
        const uint2 kv = *(const uint2*)(Krow + u * 128 + q * 8);
        const float2 k01 = unpack2(kv.x);
        const float2 k23 = unpack2(kv.y);
        p += k01.x * qreg[u].x + k01.y * qreg[u].y + k23.x * qreg[u].z + k23.y * qreg[u].w;
      }
    }
    p += __shfl_down(p, 8, 16);
    p += __shfl_down(p, 4, 16);
    p += __shfl_down(p, 2, 16);
    p += __shfl_down(p, 1, 16);
    if (q == 0 && ji < c) vsh[wave][ji] = p;
  }
  // same-wave LDS: in-order DS pipe, no barrier needed.

  // Step 2: aval[mi] = sum_ji Wsh[ji*c+mi] * v[ji]  (lane = mi)
  float aval = 0.0f;
  if (lane < c) {
    for (int ji = 0; ji < c; ji++)
      aval += Wsh[ji * c + lane] * vsh[wave][ji];
  }

  // Step 3: in-wave softmax over {aval[0..c), pnw[n] at diag, 512-c-1 zeros}
  const float dlg = pnw[n];
  float mval = (lane < c) ? aval : -INFINITY;
#pragma unroll
  for (int off = 32; off; off >>= 1) mval = fmaxf(mval, __shfl_xor(mval, off));
  const float colmax = fmaxf(mval, fmaxf(dlg, 0.0f));
  const float e = (lane < c) ? __expf(aval - colmax) : 0.0f;
  float sum = e;
#pragma unroll
  for (int off = 32; off; off >>= 1) sum += __shfl_xor(sum, off);
  const float denom = sum + __expf(dlg - colmax)
                    + (float)(NN - c - 1) * __expf(-colmax);
  const float inv = 1.0f / denom;

  // Step 4/5: Att column scatter (rest of column stays zero-filled)
  float* Acol = Att + (size_t)b * NN * NN + n;
  if (lane < c) {
    const float attv = e * inv;
    ash[wave][lane] = attv;
    Acol[(size_t)lsh[lane] * NN] = attv;
  }
  if (lane == c) {
    const float dv = __expf(dlg - colmax) * inv;
    ash[wave][c] = dv;
    Acol[(size_t)n * NN] = dv;
  }

  // Step 6: agg[b,n,:] = sum_{mi<=c} ash[mi] * xt[b,lsh[mi],:]
  const char* xtb = (const char*)(xt + (size_t)b * NN * SS);
  f32x4 acc = (f32x4)0.0f;
  for (int mi = 0; mi <= c; mi++) {
    const float a = ash[wave][mi];
    const uint2 v = *(const uint2*)(xtb + lshB[mi] + lane * 8);
    acc.x += a * __uint_as_float(v.x << 16);
    acc.y += a * __uint_as_float(v.x & 0xffff0000u);
    acc.z += a * __uint_as_float(v.y << 16);
    acc.w += a * __uint_as_float(v.y & 0xffff0000u);
  }
  *(f32x4*)(agg + ((size_t)b * NN + n) * SS + lane * 4) = acc;
}

// ---------------------------------------------------------------------------
extern "C" void kernel_launch(void* const* d_in, const int* in_sizes, int n_in,
                              void* d_out, int out_size, void* d_ws, size_t ws_size,
                              hipStream_t stream) {
  const float* x    = (const float*)d_in[0];
  const float* adj  = (const float*)d_in[1];
  const float* W    = (const float*)d_in[2];
  const float* pnw  = (const float*)d_in[3];
  const float* Wq_w = (const float*)d_in[4];
  const float* Wq_b = (const float*)d_in[5];
  const float* Wk_w = (const float*)d_in[6];
  const float* Wk_b = (const float*)d_in[7];

  float* agg = (float*)d_out;                        // (B,N,S)
  float* Att = (float*)d_out + (size_t)BB * NN * SS; // (B,N,N)

  char* p = (char*)d_ws;
  unsigned short* xp  = (unsigned short*)p; p += (size_t)BB * SS * 1024 * 2;  // 33.55 MB
  unsigned short* Wqp = (unsigned short*)p; p += (size_t)NN * 1024 * 2;       // 1.05 MB
  unsigned short* Wkp = (unsigned short*)p; p += (size_t)NN * 1024 * 2;       // 1.05 MB
  float* Qt  = (float*)p; p += (size_t)BB * NN * SS * 4;                      // 33.55 MB (f32)
  unsigned short* Kt  = (unsigned short*)p; p += (size_t)BB * NN * SS * 2;    // 16.78 MB
  unsigned short* xt  = (unsigned short*)p; p += (size_t)BB * NN * SS * 2;    // 16.78 MB
  float* Wsub = (float*)p; p += (size_t)NN * MAXC * MAXC * 4;                 // 8.39 MB (bound)
  int* col_idx = (int*)p; p += (size_t)NN * MAXC * 4;
  int* col_cnt = (int*)p; p += NN * 4;
  int* col_off = (int*)p;

  k_collist<<<dim3(NN), dim3(64), 0, stream>>>(adj, col_idx, col_cnt);
  k_wsub<<<dim3(NN), dim3(64), 0, stream>>>(W, col_idx, col_cnt, col_off, Wsub);
  k_xprep<<<dim3(SS / 32, NN / 32, BB), dim3(32, 8), 0, stream>>>(x, xp, xt, Att);
  k_wsplit<<<dim3(NN, 2), dim3(128), 0, stream>>>(Wq_w, Wk_w, Wqp, Wkp);

  k_lin2<<<dim3(512), dim3(256), 0, stream>>>(Wqp, Wkp, Wq_b, Wk_b, xp, Qt, Kt);
  k_fused<<<dim3(8192), dim3(256), 0, stream>>>(Qt, Kt, xt, Wsub, pnw,
                                                col_idx, col_cnt, col_off,
                                                Att, agg);
}

// Round 15
// 128.445 us; speedup vs baseline: 1.6032x; 1.2406x over previous
//
#include <hip/hip_runtime.h>
#include <hip/hip_fp16.h>
#include <cstdint>
#include <cmath>

#define BB 64
#define SS 256
#define NN 512
#define MAXC 64   // max nonzeros per adj column (mean ~25.6, true max ~46)

typedef float f32x4 __attribute__((ext_vector_type(4)));
typedef _Float16 half8 __attribute__((ext_vector_type(8)));

__device__ __forceinline__ unsigned short f2h(float f) {
  return __half_as_ushort(__float2half(f));
}
__device__ __forceinline__ float2 unpackh2(uint32_t u) {
  return make_float2(__half2float(__ushort_as_half((unsigned short)(u & 0xffffu))),
                     __half2float(__ushort_as_half((unsigned short)(u >> 16))));
}

__device__ __forceinline__ void gload_lds16(const void* g, void* s) {
  __builtin_amdgcn_global_load_lds(
      (const __attribute__((address_space(1))) uint32_t*)g,
      (__attribute__((address_space(3))) uint32_t*)s, 16, 0, 0);
}

// ---------------------------------------------------------------------------
// K0: per-column adjacency lists (ascending m, ballot compaction).
__global__ __launch_bounds__(64) void k_collist(const float* __restrict__ adj,
                                                int* __restrict__ col_idx,
                                                int* __restrict__ col_cnt) {
  const int n = blockIdx.x;
  const int lane = threadIdx.x;
  int cnt = 0;
  for (int m0 = 0; m0 < NN; m0 += 64) {
    const int m = m0 + lane;
    const float a = adj[(size_t)m * NN + n];
    unsigned long long mask = __ballot(a != 0.0f);
    const int prefix = __popcll(mask & ((1ull << lane) - 1ull));
    if (a != 0.0f && cnt + prefix < MAXC) col_idx[n * MAXC + cnt + prefix] = m;
    cnt += __popcll(mask);
  }
  if (lane == 0) col_cnt[n] = (cnt > MAXC) ? MAXC : cnt;
}

// K0b: packed W sub-blocks + per-block prefix scan.
// Wsub[off[n] + ji*c + mi] = W[lsh[mi]][lsh[ji]],  off[n] = sum_{i<n} cnt[i]^2
__global__ __launch_bounds__(64) void k_wsub(const float* __restrict__ W,
                                             const int* __restrict__ col_idx,
                                             const int* __restrict__ col_cnt,
                                             int* __restrict__ col_off,
                                             float* __restrict__ Wsub) {
  const int n = blockIdx.x;
  const int lane = threadIdx.x;
  __shared__ int lsh[MAXC];
  int pre = 0;
#pragma unroll
  for (int i0 = 0; i0 < NN; i0 += 64) {
    const int i = i0 + lane;
    const int cc = col_cnt[i];
    pre += (i < n) ? cc * cc : 0;
  }
#pragma unroll
  for (int off = 32; off; off >>= 1) pre += __shfl_xor(pre, off);
  if (lane == 0) col_off[n] = pre;

  const int c = col_cnt[n];
  if (lane < c) lsh[lane] = col_idx[n * MAXC + lane];
  __syncthreads();
  if (lane < c) {
    const float* Wm = W + (size_t)lsh[lane] * NN;
    float* dst = Wsub + pre + lane;
    for (int ji = 0; ji < c; ji++) dst[(size_t)ji * c] = Wm[lsh[ji]];
  }
}

// ---------------------------------------------------------------------------
// K1: fused x-prep: x (B,S,N) f32 -> xp (B*S,512) f16, xt (B,N,S) f16,
//     plus zero-fill of the Att output region.
__global__ __launch_bounds__(256) void k_xprep(const float* __restrict__ x,
                                               unsigned short* __restrict__ xp,
                                               unsigned short* __restrict__ xt,
                                               float* __restrict__ Att) {
  __shared__ float tile[32][33];
  const int b = blockIdx.z;
  const int s0 = blockIdx.x * 32, n0 = blockIdx.y * 32;
  const float* xb = x + (size_t)b * SS * NN;
  const int tx = threadIdx.x, ty = threadIdx.y;  // (32,8)
#pragma unroll
  for (int i = ty; i < 32; i += 8) {
    const float v = xb[(size_t)(s0 + i) * NN + n0 + tx];
    tile[i][tx] = v;
    xp[(size_t)(b * SS + s0 + i) * 512 + n0 + tx] = f2h(v);
  }
  {
    const int bid = (blockIdx.z * 16 + blockIdx.y) * 8 + blockIdx.x;
    const int t = ty * 32 + tx;
    f32x4* dst = (f32x4*)(Att + (size_t)bid * 2048);
    const f32x4 z = (f32x4)0.0f;
    dst[t] = z;
    dst[t + 256] = z;
  }
  __syncthreads();
  unsigned short* xtb = xt + (size_t)b * NN * SS;
#pragma unroll
  for (int i = ty; i < 32; i += 8)
    xtb[(size_t)(n0 + i) * SS + s0 + tx] = f2h(tile[tx][i]);
}

// K1b: weight conversion to f16 (both Wq and Wk)
__global__ __launch_bounds__(128) void k_wsplit(const float* __restrict__ Wq,
                                                const float* __restrict__ Wk,
                                                unsigned short* __restrict__ Wqp,
                                                unsigned short* __restrict__ Wkp) {
  const int n = blockIdx.x;
  const float* src = blockIdx.y ? Wk : Wq;
  unsigned short* dst = blockIdx.y ? Wkp : Wqp;
  const int k = threadIdx.x * 4;
  float4 v = *(const float4*)(src + (size_t)n * NN + k);
  ushort4 o;
  o.x = f2h(v.x); o.y = f2h(v.y); o.z = f2h(v.z); o.w = f2h(v.w);
  *(ushort4*)(dst + (size_t)n * 512 + k) = o;
}

// ---------------------------------------------------------------------------
// K3: BOTH Linears in one block (shared X staging), 2-phase prefetch pipeline.
// Single-pass f16 GEMM (K=512 -> 16 K-steps). Q out f32, K out f16.
__global__ __launch_bounds__(256, 2) void k_lin2(const unsigned short* __restrict__ Wqp,
                                                 const unsigned short* __restrict__ Wkp,
                                                 const float* __restrict__ bq,
                                                 const float* __restrict__ bk,
                                                 const unsigned short* __restrict__ xp,
                                                 float* __restrict__ Qt,
                                                 unsigned short* __restrict__ Kt) {
  __shared__ __align__(16) char sm[49152];
  const int t = threadIdx.x;
  const int w = t >> 6, l = t & 63;
  const int id = blockIdx.x;
  const int xcd = id & 7, sub = id >> 3;
  const int bn0 = (xcd * 16 + (sub >> 2)) * 128;  // r = b*256+s
  const int bm0 = (sub & 3) * 128;                // n

  const int swz = (((l & 3) ^ ((l >> 3) & 3))) * 16;
  const char* srcb[6];
  char* dstb[6];
#pragma unroll
  for (int i = 0; i < 6; i++) {
    const int ch = w * 6 + i;
    const int panel = ch >> 3, rowgrp = ch & 7;
    const int row = rowgrp * 16 + (l >> 2);
    const char* g0 = (panel == 0) ? (const char*)Wqp
                   : (panel == 1) ? (const char*)Wkp : (const char*)xp;
    const int gr = ((panel == 2) ? bn0 : bm0) + row;
    srcb[i] = g0 + (size_t)gr * 1024 + swz;
    dstb[i] = sm + panel * 8192 + rowgrp * 1024 + l * 16;
  }

  const int fr = l & 15, fg = l >> 4;
  const int mrow = (w >> 1) * 64, ncol = (w & 1) * 64;
  const int slot = (fg ^ ((fr >> 1) & 3)) * 16;
  int offQ[4], offK[4], offB[4];
#pragma unroll
  for (int fm = 0; fm < 4; fm++) {
    offQ[fm] = (mrow + fm * 16 + fr) * 64 + slot;
    offK[fm] = 8192 + (mrow + fm * 16 + fr) * 64 + slot;
    offB[fm] = 16384 + (ncol + fm * 16 + fr) * 64 + slot;
  }

  f32x4 accq[4][4], acck[4][4];
#pragma unroll
  for (int i = 0; i < 4; i++)
#pragma unroll
    for (int j = 0; j < 4; j++) { accq[i][j] = (f32x4)0.0f; acck[i][j] = (f32x4)0.0f; }

#pragma unroll
  for (int i = 0; i < 6; i++) gload_lds16(srcb[i], dstb[i]);
  __syncthreads();

  int cur = 0;
  for (int kk = 0; kk < 16; kk++) {
    if (kk + 1 < 16) {
      const int ko = (kk + 1) * 64;
      const int boff = (cur ^ 1) * 24576;
#pragma unroll
      for (int i = 0; i < 6; i++)
        gload_lds16(srcb[i] + ko, dstb[i] + boff);
    }
    const char* base = sm + cur * 24576;
    half8 afq[4], afk[4];
#pragma unroll
    for (int fm = 0; fm < 4; fm++) {
      afq[fm] = *(const half8*)(base + offQ[fm]);
      afk[fm] = *(const half8*)(base + offK[fm]);
    }
#pragma unroll
    for (int fn = 0; fn < 4; fn++) {
      const half8 bv = *(const half8*)(base + offB[fn]);
#pragma unroll
      for (int fm = 0; fm < 4; fm++) {
        accq[fm][fn] = __builtin_amdgcn_mfma_f32_16x16x32_f16(afq[fm], bv, accq[fm][fn], 0, 0, 0);
        acck[fm][fn] = __builtin_amdgcn_mfma_f32_16x16x32_f16(afk[fm], bv, acck[fm][fn], 0, 0, 0);
      }
    }
    __syncthreads();
    cur ^= 1;
  }

  // epilogue: D col = lane&15 (-> r), row = (lane>>4)*4+q (-> n)
  const int b = bn0 >> 8;
  const int sbase = (bn0 & 255) + ncol;
#pragma unroll
  for (int fm = 0; fm < 4; fm++) {
#pragma unroll
    for (int q = 0; q < 4; q++) {
      const int n = bm0 + mrow + fm * 16 + fg * 4 + q;
      const float bvq = bq[n];
      const float bvk = bk[n];
#pragma unroll
      for (int fn = 0; fn < 4; fn++) {
        const int s = sbase + fn * 16 + fr;
        Qt[((size_t)b * NN + n) * SS + s] = accq[fm][fn][q] + bvq;
        Kt[((size_t)b * NN + n) * SS + s] = f2h(acck[fm][fn][q] + bvk);
      }
    }
  }
}

// ---------------------------------------------------------------------------
// K4: fused sparse stage — ONE WAVE per (n,b) column; 4 batches per block
// (per-XCD hot set {4xK, 4xxt, Wsub} < 4MiB L2); one __syncthreads.
// K f16 + xt f16, Q f32. lshB = precomputed row byte offsets.
__global__ __launch_bounds__(256) void k_fused(const float* __restrict__ Qt,
                                               const unsigned short* __restrict__ Kt,
                                               const unsigned short* __restrict__ xt,
                                               const float* __restrict__ Wsub,
                                               const float* __restrict__ pnw,
                                               const int* __restrict__ col_idx,
                                               const int* __restrict__ col_cnt,
                                               const int* __restrict__ col_off,
                                               float* __restrict__ Att,
                                               float* __restrict__ agg) {
  // XCD-exclusive swizzle: xcd = id&7 owns batches [xcd*8, xcd*8+8).
  const int id = blockIdx.x;          // 0..8191
  const int xcd = id & 7;
  const int r = id >> 3;              // 0..1023
  const int n = r & 511;
  const int bgrp = r >> 9;            // 0..1
  const int t = threadIdx.x;
  const int wave = t >> 6, lane = t & 63;
  const int b = (xcd << 3) + (bgrp << 2) + wave;

  __shared__ int   lsh[MAXC + 1];
  __shared__ int   lshB[MAXC + 1];    // lsh * 512 (byte offset of a f16 row)
  __shared__ float Wsh[MAXC * MAXC];
  __shared__ float vsh[4][MAXC];
  __shared__ float ash[4][MAXC + 1];

  const int c = col_cnt[n];
  if (t < c) {
    const int v = col_idx[n * MAXC + t];
    lsh[t] = v;
    lshB[t] = v << 9;
  }
  if (t == c) { lsh[c] = n; lshB[c] = n << 9; }
  {
    const int cc = c * c;
    const float* Wp = Wsub + col_off[n];
    for (int i = t; i < cc; i += 256) Wsh[i] = Wp[i];
  }
  __syncthreads();   // the only block barrier

  // Step 1: v[ji] = <K[b,lsh[ji],:], Q[b,n,:]>; 16 lanes/dot, 4 dots in flight.
  const int g = lane >> 4, q = lane & 15;
  const float* Qrow = Qt + ((size_t)b * NN + n) * SS;
  const char* Kb = (const char*)(Kt + (size_t)b * NN * SS);
  f32x4 qreg[4];
#pragma unroll
  for (int u = 0; u < 4; u++)
    qreg[u] = *(const f32x4*)(Qrow + (u * 16 + q) * 4);
  for (int j0 = 0; j0 < c; j0 += 4) {
    const int ji = j0 + g;
    float p = 0.0f;
    if (ji < c) {
      const char* Krow = Kb + lshB[ji];
#pragma unroll
      for (int u = 0; u < 4; u++) {
        const uint2 kv = *(const uint2*)(Krow + u * 128 + q * 8);
        const float2 k01 = unpackh2(kv.x);
        const float2 k23 = unpackh2(kv.y);
        p += k01.x * qreg[u].x + k01.y * qreg[u].y + k23.x * qreg[u].z + k23.y * qreg[u].w;
      }
    }
    p += __shfl_down(p, 8, 16);
    p += __shfl_down(p, 4, 16);
    p += __shfl_down(p, 2, 16);
    p += __shfl_down(p, 1, 16);
    if (q == 0 && ji < c) vsh[wave][ji] = p;
  }
  // same-wave LDS: in-order DS pipe, no barrier needed.

  // Step 2: aval[mi] = sum_ji Wsh[ji*c+mi] * v[ji]  (lane = mi)
  float aval = 0.0f;
  if (lane < c) {
    for (int ji = 0; ji < c; ji++)
      aval += Wsh[ji * c + lane] * vsh[wave][ji];
  }

  // Step 3: in-wave softmax over {aval[0..c), pnw[n] at diag, 512-c-1 zeros}
  const float dlg = pnw[n];
  float mval = (lane < c) ? aval : -INFINITY;
#pragma unroll
  for (int off = 32; off; off >>= 1) mval = fmaxf(mval, __shfl_xor(mval, off));
  const float colmax = fmaxf(mval, fmaxf(dlg, 0.0f));
  const float e = (lane < c) ? __expf(aval - colmax) : 0.0f;
  float sum = e;
#pragma unroll
  for (int off = 32; off; off >>= 1) sum += __shfl_xor(sum, off);
  const float denom = sum + __expf(dlg - colmax)
                    + (float)(NN - c - 1) * __expf(-colmax);
  const float inv = 1.0f / denom;

  // Step 4/5: Att column scatter (rest of column stays zero-filled)
  float* Acol = Att + (size_t)b * NN * NN + n;
  if (lane < c) {
    const float attv = e * inv;
    ash[wave][lane] = attv;
    Acol[(size_t)lsh[lane] * NN] = attv;
  }
  if (lane == c) {
    const float dv = __expf(dlg - colmax) * inv;
    ash[wave][c] = dv;
    Acol[(size_t)n * NN] = dv;
  }

  // Step 6: agg[b,n,:] = sum_{mi<=c} ash[mi] * xt[b,lsh[mi],:]
  const char* xtb = (const char*)(xt + (size_t)b * NN * SS);
  f32x4 acc = (f32x4)0.0f;
  for (int mi = 0; mi <= c; mi++) {
    const float a = ash[wave][mi];
    const uint2 v = *(const uint2*)(xtb + lshB[mi] + lane * 8);
    const float2 x01 = unpackh2(v.x);
    const float2 x23 = unpackh2(v.y);
    acc.x += a * x01.x;
    acc.y += a * x01.y;
    acc.z += a * x23.x;
    acc.w += a * x23.y;
  }
  *(f32x4*)(agg + ((size_t)b * NN + n) * SS + lane * 4) = acc;
}

// ---------------------------------------------------------------------------
extern "C" void kernel_launch(void* const* d_in, const int* in_sizes, int n_in,
                              void* d_out, int out_size, void* d_ws, size_t ws_size,
                              hipStream_t stream) {
  const float* x    = (const float*)d_in[0];
  const float* adj  = (const float*)d_in[1];
  const float* W    = (const float*)d_in[2];
  const float* pnw  = (const float*)d_in[3];
  const float* Wq_w = (const float*)d_in[4];
  const float* Wq_b = (const float*)d_in[5];
  const float* Wk_w = (const float*)d_in[6];
  const float* Wk_b = (const float*)d_in[7];

  float* agg = (float*)d_out;                        // (B,N,S)
  float* Att = (float*)d_out + (size_t)BB * NN * SS; // (B,N,N)

  char* p = (char*)d_ws;
  unsigned short* xp  = (unsigned short*)p; p += (size_t)BB * SS * 512 * 2;   // 16.78 MB (f16)
  unsigned short* Wqp = (unsigned short*)p; p += (size_t)NN * 512 * 2;        // 0.52 MB
  unsigned short* Wkp = (unsigned short*)p; p += (size_t)NN * 512 * 2;        // 0.52 MB
  float* Qt  = (float*)p; p += (size_t)BB * NN * SS * 4;                      // 33.55 MB (f32)
  unsigned short* Kt  = (unsigned short*)p; p += (size_t)BB * NN * SS * 2;    // 16.78 MB (f16)
  unsigned short* xt  = (unsigned short*)p; p += (size_t)BB * NN * SS * 2;    // 16.78 MB (f16)
  float* Wsub = (float*)p; p += (size_t)NN * MAXC * MAXC * 4;                 // 8.39 MB (bound)
  int* col_idx = (int*)p; p += (size_t)NN * MAXC * 4;
  int* col_cnt = (int*)p; p += NN * 4;
  int* col_off = (int*)p;

  k_collist<<<dim3(NN), dim3(64), 0, stream>>>(adj, col_idx, col_cnt);
  k_wsub<<<dim3(NN), dim3(64), 0, stream>>>(W, col_idx, col_cnt, col_off, Wsub);
  k_xprep<<<dim3(SS / 32, NN / 32, BB), dim3(32, 8), 0, stream>>>(x, xp, xt, Att);
  k_wsplit<<<dim3(NN, 2), dim3(128), 0, stream>>>(Wq_w, Wk_w, Wqp, Wkp);

  k_lin2<<<dim3(512), dim3(256), 0, stream>>>(Wqp, Wkp, Wq_b, Wk_b, xp, Qt, Kt);
  k_fused<<<dim3(8192), dim3(256), 0, stream>>>(Qt, Kt, xt, Wsub, pnw,
                                                col_idx, col_cnt, col_off,
                                                Att, agg);
}

// Round 16
// 123.813 us; speedup vs baseline: 1.6632x; 1.0374x over previous
//
#include <hip/hip_runtime.h>
#include <hip/hip_fp16.h>
#include <cstdint>
#include <cmath>

#define BB 64
#define SS 256
#define NN 512
#define MAXC 64   // max nonzeros per adj column (mean ~25.6, true max ~46)

typedef float f32x4 __attribute__((ext_vector_type(4)));
typedef _Float16 half8 __attribute__((ext_vector_type(8)));
typedef _Float16 h2 __attribute__((ext_vector_type(2)));

__device__ __forceinline__ unsigned short f2h(float f) {
  return __half_as_ushort(__float2half(f));
}
__device__ __forceinline__ h2 u2h2(uint32_t u) {
  union { uint32_t u; h2 h; } c; c.u = u; return c.h;
}
__device__ __forceinline__ float2 unpackh2(uint32_t u) {
  return make_float2(__half2float(__ushort_as_half((unsigned short)(u & 0xffffu))),
                     __half2float(__ushort_as_half((unsigned short)(u >> 16))));
}

__device__ __forceinline__ void gload_lds16(const void* g, void* s) {
  __builtin_amdgcn_global_load_lds(
      (const __attribute__((address_space(1))) uint32_t*)g,
      (__attribute__((address_space(3))) uint32_t*)s, 16, 0, 0);
}

// ---------------------------------------------------------------------------
// K0: per-column adjacency lists (ascending m, ballot compaction).
// 4 columns per block (one per wave) for occupancy.
__global__ __launch_bounds__(256) void k_collist(const float* __restrict__ adj,
                                                 int* __restrict__ col_idx,
                                                 int* __restrict__ col_cnt) {
  const int n = blockIdx.x * 4 + (threadIdx.x >> 6);
  const int lane = threadIdx.x & 63;
  int cnt = 0;
  for (int m0 = 0; m0 < NN; m0 += 64) {
    const int m = m0 + lane;
    const float a = adj[(size_t)m * NN + n];
    unsigned long long mask = __ballot(a != 0.0f);
    const int prefix = __popcll(mask & ((1ull << lane) - 1ull));
    if (a != 0.0f && cnt + prefix < MAXC) col_idx[n * MAXC + cnt + prefix] = m;
    cnt += __popcll(mask);
  }
  if (lane == 0) col_cnt[n] = (cnt > MAXC) ? MAXC : cnt;
}

// K0b: packed W sub-blocks + per-block prefix scan. 4 waves split the ji-loop.
// Wsub[off[n] + ji*c + mi] = W[lsh[mi]][lsh[ji]],  off[n] = sum_{i<n} cnt[i]^2
__global__ __launch_bounds__(256) void k_wsub(const float* __restrict__ W,
                                              const int* __restrict__ col_idx,
                                              const int* __restrict__ col_cnt,
                                              int* __restrict__ col_off,
                                              float* __restrict__ Wsub) {
  const int n = blockIdx.x;
  const int t = threadIdx.x;
  const int wave = t >> 6, lane = t & 63;
  __shared__ int lsh[MAXC];
  __shared__ int preSh;
  const int c = col_cnt[n];
  if (wave == 0) {
    int pre = 0;
#pragma unroll
    for (int i0 = 0; i0 < NN; i0 += 64) {
      const int i = i0 + lane;
      const int cc = col_cnt[i];
      pre += (i < n) ? cc * cc : 0;
    }
#pragma unroll
    for (int off = 32; off; off >>= 1) pre += __shfl_xor(pre, off);
    if (lane == 0) { col_off[n] = pre; preSh = pre; }
    if (lane < c) lsh[lane] = col_idx[n * MAXC + lane];
  }
  __syncthreads();
  if (lane < c) {
    const float* Wm = W + (size_t)lsh[lane] * NN;
    float* dst = Wsub + preSh + lane;
    for (int ji = wave; ji < c; ji += 4)
      dst[(size_t)ji * c] = Wm[lsh[ji]];
  }
}

// ---------------------------------------------------------------------------
// K1: fused x-prep: x (B,S,N) f32 -> xp (B*S,512) f16, xt (B,N,S) f16,
//     plus zero-fill of the Att output region.
__global__ __launch_bounds__(256) void k_xprep(const float* __restrict__ x,
                                               unsigned short* __restrict__ xp,
                                               unsigned short* __restrict__ xt,
                                               float* __restrict__ Att) {
  __shared__ float tile[32][33];
  const int b = blockIdx.z;
  const int s0 = blockIdx.x * 32, n0 = blockIdx.y * 32;
  const float* xb = x + (size_t)b * SS * NN;
  const int tx = threadIdx.x, ty = threadIdx.y;  // (32,8)
#pragma unroll
  for (int i = ty; i < 32; i += 8) {
    const float v = xb[(size_t)(s0 + i) * NN + n0 + tx];
    tile[i][tx] = v;
    xp[(size_t)(b * SS + s0 + i) * 512 + n0 + tx] = f2h(v);
  }
  {
    const int bid = (blockIdx.z * 16 + blockIdx.y) * 8 + blockIdx.x;
    const int t = ty * 32 + tx;
    f32x4* dst = (f32x4*)(Att + (size_t)bid * 2048);
    const f32x4 z = (f32x4)0.0f;
    dst[t] = z;
    dst[t + 256] = z;
  }
  __syncthreads();
  unsigned short* xtb = xt + (size_t)b * NN * SS;
#pragma unroll
  for (int i = ty; i < 32; i += 8)
    xtb[(size_t)(n0 + i) * SS + s0 + tx] = f2h(tile[tx][i]);
}

// K1b: weight conversion to f16 (both Wq and Wk)
__global__ __launch_bounds__(128) void k_wsplit(const float* __restrict__ Wq,
                                                const float* __restrict__ Wk,
                                                unsigned short* __restrict__ Wqp,
                                                unsigned short* __restrict__ Wkp) {
  const int n = blockIdx.x;
  const float* src = blockIdx.y ? Wk : Wq;
  unsigned short* dst = blockIdx.y ? Wkp : Wqp;
  const int k = threadIdx.x * 4;
  float4 v = *(const float4*)(src + (size_t)n * NN + k);
  ushort4 o;
  o.x = f2h(v.x); o.y = f2h(v.y); o.z = f2h(v.z); o.w = f2h(v.w);
  *(ushort4*)(dst + (size_t)n * 512 + k) = o;
}

// ---------------------------------------------------------------------------
// K3: BOTH Linears in one block (shared X staging), 2-phase prefetch pipeline.
// Single-pass f16 GEMM (K=512 -> 16 K-steps). Q out f16, K out f16.
__global__ __launch_bounds__(256, 2) void k_lin2(const unsigned short* __restrict__ Wqp,
                                                 const unsigned short* __restrict__ Wkp,
                                                 const float* __restrict__ bq,
                                                 const float* __restrict__ bk,
                                                 const unsigned short* __restrict__ xp,
                                                 unsigned short* __restrict__ Qt,
                                                 unsigned short* __restrict__ Kt) {
  __shared__ __align__(16) char sm[49152];
  const int t = threadIdx.x;
  const int w = t >> 6, l = t & 63;
  const int id = blockIdx.x;
  const int xcd = id & 7, sub = id >> 3;
  const int bn0 = (xcd * 16 + (sub >> 2)) * 128;  // r = b*256+s
  const int bm0 = (sub & 3) * 128;                // n

  const int swz = (((l & 3) ^ ((l >> 3) & 3))) * 16;
  const char* srcb[6];
  char* dstb[6];
#pragma unroll
  for (int i = 0; i < 6; i++) {
    const int ch = w * 6 + i;
    const int panel = ch >> 3, rowgrp = ch & 7;
    const int row = rowgrp * 16 + (l >> 2);
    const char* g0 = (panel == 0) ? (const char*)Wqp
                   : (panel == 1) ? (const char*)Wkp : (const char*)xp;
    const int gr = ((panel == 2) ? bn0 : bm0) + row;
    srcb[i] = g0 + (size_t)gr * 1024 + swz;
    dstb[i] = sm + panel * 8192 + rowgrp * 1024 + l * 16;
  }

  const int fr = l & 15, fg = l >> 4;
  const int mrow = (w >> 1) * 64, ncol = (w & 1) * 64;
  const int slot = (fg ^ ((fr >> 1) & 3)) * 16;
  int offQ[4], offK[4], offB[4];
#pragma unroll
  for (int fm = 0; fm < 4; fm++) {
    offQ[fm] = (mrow + fm * 16 + fr) * 64 + slot;
    offK[fm] = 8192 + (mrow + fm * 16 + fr) * 64 + slot;
    offB[fm] = 16384 + (ncol + fm * 16 + fr) * 64 + slot;
  }

  f32x4 accq[4][4], acck[4][4];
#pragma unroll
  for (int i = 0; i < 4; i++)
#pragma unroll
    for (int j = 0; j < 4; j++) { accq[i][j] = (f32x4)0.0f; acck[i][j] = (f32x4)0.0f; }

#pragma unroll
  for (int i = 0; i < 6; i++) gload_lds16(srcb[i], dstb[i]);
  __syncthreads();

  int cur = 0;
  for (int kk = 0; kk < 16; kk++) {
    if (kk + 1 < 16) {
      const int ko = (kk + 1) * 64;
      const int boff = (cur ^ 1) * 24576;
#pragma unroll
      for (int i = 0; i < 6; i++)
        gload_lds16(srcb[i] + ko, dstb[i] + boff);
    }
    const char* base = sm + cur * 24576;
    half8 afq[4], afk[4];
#pragma unroll
    for (int fm = 0; fm < 4; fm++) {
      afq[fm] = *(const half8*)(base + offQ[fm]);
      afk[fm] = *(const half8*)(base + offK[fm]);
    }
#pragma unroll
    for (int fn = 0; fn < 4; fn++) {
      const half8 bv = *(const half8*)(base + offB[fn]);
#pragma unroll
      for (int fm = 0; fm < 4; fm++) {
        accq[fm][fn] = __builtin_amdgcn_mfma_f32_16x16x32_f16(afq[fm], bv, accq[fm][fn], 0, 0, 0);
        acck[fm][fn] = __builtin_amdgcn_mfma_f32_16x16x32_f16(afk[fm], bv, acck[fm][fn], 0, 0, 0);
      }
    }
    __syncthreads();
    cur ^= 1;
  }

  // epilogue: D col = lane&15 (-> r), row = (lane>>4)*4+q (-> n)
  const int b = bn0 >> 8;
  const int sbase = (bn0 & 255) + ncol;
#pragma unroll
  for (int fm = 0; fm < 4; fm++) {
#pragma unroll
    for (int q = 0; q < 4; q++) {
      const int n = bm0 + mrow + fm * 16 + fg * 4 + q;
      const float bvq = bq[n];
      const float bvk = bk[n];
#pragma unroll
      for (int fn = 0; fn < 4; fn++) {
        const int s = sbase + fn * 16 + fr;
        Qt[((size_t)b * NN + n) * SS + s] = f2h(accq[fm][fn][q] + bvq);
        Kt[((size_t)b * NN + n) * SS + s] = f2h(acck[fm][fn][q] + bvk);
      }
    }
  }
}

// ---------------------------------------------------------------------------
// K4: fused sparse stage — ONE WAVE per (n,b) column; 4 batches per block
// (per-XCD hot set < 4MiB L2); one __syncthreads.
// K,Q,xt all f16. Step-1 dots on v_dot2_f32_f16 (packed f16, f32 accumulate).
__global__ __launch_bounds__(256) void k_fused(const unsigned short* __restrict__ Qt,
                                               const unsigned short* __restrict__ Kt,
                                               const unsigned short* __restrict__ xt,
                                               const float* __restrict__ Wsub,
                                               const float* __restrict__ pnw,
                                               const int* __restrict__ col_idx,
                                               const int* __restrict__ col_cnt,
                                               const int* __restrict__ col_off,
                                               float* __restrict__ Att,
                                               float* __restrict__ agg) {
  // XCD-exclusive swizzle: xcd = id&7 owns batches [xcd*8, xcd*8+8).
  const int id = blockIdx.x;          // 0..8191
  const int xcd = id & 7;
  const int r = id >> 3;              // 0..1023
  const int n = r & 511;
  const int bgrp = r >> 9;            // 0..1
  const int t = threadIdx.x;
  const int wave = t >> 6, lane = t & 63;
  const int b = (xcd << 3) + (bgrp << 2) + wave;

  __shared__ int   lsh[MAXC + 1];
  __shared__ int   lshB[MAXC + 1];    // lsh * 512 (byte offset of a f16 row)
  __shared__ float Wsh[MAXC * MAXC];
  __shared__ float vsh[4][MAXC];
  __shared__ float ash[4][MAXC + 1];

  const int c = col_cnt[n];
  if (t < c) {
    const int v = col_idx[n * MAXC + t];
    lsh[t] = v;
    lshB[t] = v << 9;
  }
  if (t == c) { lsh[c] = n; lshB[c] = n << 9; }
  {
    const int cc = c * c;
    const float* Wp = Wsub + col_off[n];
    for (int i = t; i < cc; i += 256) Wsh[i] = Wp[i];
  }
  __syncthreads();   // the only block barrier

  // Step 1: v[ji] = <K[b,lsh[ji],:], Q[b,n,:]>; 16 lanes/dot, 4 dots in
  // flight, fdot2 packed-f16 MACs.
  const int g = lane >> 4, q = lane & 15;
  const unsigned short* Qrow = Qt + ((size_t)b * NN + n) * SS;
  const char* Kb = (const char*)(Kt + (size_t)b * NN * SS);
  h2 qh[4][2];
#pragma unroll
  for (int u = 0; u < 4; u++) {
    const uint2 v = *(const uint2*)(Qrow + (u * 16 + q) * 4);
    qh[u][0] = u2h2(v.x);
    qh[u][1] = u2h2(v.y);
  }
  for (int j0 = 0; j0 < c; j0 += 4) {
    const int ji = j0 + g;
    float p = 0.0f;
    if (ji < c) {
      const char* Krow = Kb + lshB[ji];
#pragma unroll
      for (int u = 0; u < 4; u++) {
        const uint2 kv = *(const uint2*)(Krow + u * 128 + q * 8);
        p = __builtin_amdgcn_fdot2(u2h2(kv.x), qh[u][0], p, false);
        p = __builtin_amdgcn_fdot2(u2h2(kv.y), qh[u][1], p, false);
      }
    }
    p += __shfl_down(p, 8, 16);
    p += __shfl_down(p, 4, 16);
    p += __shfl_down(p, 2, 16);
    p += __shfl_down(p, 1, 16);
    if (q == 0 && ji < c) vsh[wave][ji] = p;
  }
  // same-wave LDS: in-order DS pipe, no barrier needed.

  // Step 2: aval[mi] = sum_ji Wsh[ji*c+mi] * v[ji]  (lane = mi)
  float aval = 0.0f;
  if (lane < c) {
    for (int ji = 0; ji < c; ji++)
      aval += Wsh[ji * c + lane] * vsh[wave][ji];
  }

  // Step 3: in-wave softmax over {aval[0..c), pnw[n] at diag, 512-c-1 zeros}
  const float dlg = pnw[n];
  float mval = (lane < c) ? aval : -INFINITY;
#pragma unroll
  for (int off = 32; off; off >>= 1) mval = fmaxf(mval, __shfl_xor(mval, off));
  const float colmax = fmaxf(mval, fmaxf(dlg, 0.0f));
  const float e = (lane < c) ? __expf(aval - colmax) : 0.0f;
  float sum = e;
#pragma unroll
  for (int off = 32; off; off >>= 1) sum += __shfl_xor(sum, off);
  const float denom = sum + __expf(dlg - colmax)
                    + (float)(NN - c - 1) * __expf(-colmax);
  const float inv = 1.0f / denom;

  // Step 4/5: Att column scatter (rest of column stays zero-filled)
  float* Acol = Att + (size_t)b * NN * NN + n;
  if (lane < c) {
    const float attv = e * inv;
    ash[wave][lane] = attv;
    Acol[(size_t)lsh[lane] * NN] = attv;
  }
  if (lane == c) {
    const float dv = __expf(dlg - colmax) * inv;
    ash[wave][c] = dv;
    Acol[(size_t)n * NN] = dv;
  }

  // Step 6: agg[b,n,:] = sum_{mi<=c} ash[mi] * xt[b,lsh[mi],:]
  const char* xtb = (const char*)(xt + (size_t)b * NN * SS);
  f32x4 acc = (f32x4)0.0f;
  for (int mi = 0; mi <= c; mi++) {
    const float a = ash[wave][mi];
    const uint2 v = *(const uint2*)(xtb + lshB[mi] + lane * 8);
    const float2 x01 = unpackh2(v.x);
    const float2 x23 = unpackh2(v.y);
    acc.x += a * x01.x;
    acc.y += a * x01.y;
    acc.z += a * x23.x;
    acc.w += a * x23.y;
  }
  *(f32x4*)(agg + ((size_t)b * NN + n) * SS + lane * 4) = acc;
}

// ---------------------------------------------------------------------------
extern "C" void kernel_launch(void* const* d_in, const int* in_sizes, int n_in,
                              void* d_out, int out_size, void* d_ws, size_t ws_size,
                              hipStream_t stream) {
  const float* x    = (const float*)d_in[0];
  const float* adj  = (const float*)d_in[1];
  const float* W    = (const float*)d_in[2];
  const float* pnw  = (const float*)d_in[3];
  const float* Wq_w = (const float*)d_in[4];
  const float* Wq_b = (const float*)d_in[5];
  const float* Wk_w = (const float*)d_in[6];
  const float* Wk_b = (const float*)d_in[7];

  float* agg = (float*)d_out;                        // (B,N,S)
  float* Att = (float*)d_out + (size_t)BB * NN * SS; // (B,N,N)

  char* p = (char*)d_ws;
  unsigned short* xp  = (unsigned short*)p; p += (size_t)BB * SS * 512 * 2;   // 16.78 MB (f16)
  unsigned short* Wqp = (unsigned short*)p; p += (size_t)NN * 512 * 2;        // 0.52 MB
  unsigned short* Wkp = (unsigned short*)p; p += (size_t)NN * 512 * 2;        // 0.52 MB
  unsigned short* Qt  = (unsigned short*)p; p += (size_t)BB * NN * SS * 2;    // 16.78 MB (f16)
  unsigned short* Kt  = (unsigned short*)p; p += (size_t)BB * NN * SS * 2;    // 16.78 MB (f16)
  unsigned short* xt  = (unsigned short*)p; p += (size_t)BB * NN * SS * 2;    // 16.78 MB (f16)
  float* Wsub = (float*)p; p += (size_t)NN * MAXC * MAXC * 4;                 // 8.39 MB (bound)
  int* col_idx = (int*)p; p += (size_t)NN * MAXC * 4;
  int* col_cnt = (int*)p; p += NN * 4;
  int* col_off = (int*)p;

  k_collist<<<dim3(NN / 4), dim3(256), 0, stream>>>(adj, col_idx, col_cnt);
  k_wsub<<<dim3(NN), dim3(256), 0, stream>>>(W, col_idx, col_cnt, col_off, Wsub);
  k_xprep<<<dim3(SS / 32, NN / 32, BB), dim3(32, 8), 0, stream>>>(x, xp, xt, Att);
  k_wsplit<<<dim3(NN, 2), dim3(128), 0, stream>>>(Wq_w, Wk_w, Wqp, Wkp);

  k_lin2<<<dim3(512), dim3(256), 0, stream>>>(Wqp, Wkp, Wq_b, Wk_b, xp, Qt, Kt);
  k_fused<<<dim3(8192), dim3(256), 0, stream>>>(Qt, Kt, xt, Wsub, pnw,
                                                col_idx, col_cnt, col_off,
                                                Att, agg);
}

// Round 17
// 116.952 us; speedup vs baseline: 1.7608x; 1.0587x over previous
//
#include <hip/hip_runtime.h>
#include <hip/hip_fp16.h>
#include <cstdint>
#include <cmath>

#define BB 64
#define SS 256
#define NN 512
#define MAXC 64   // max nonzeros per adj column (mean ~25.6, true max ~46)

typedef float f32x4 __attribute__((ext_vector_type(4)));
typedef _Float16 half8 __attribute__((ext_vector_type(8)));

__device__ __forceinline__ unsigned short f2h(float f) {
  return __half_as_ushort(__float2half(f));
}
__device__ __forceinline__ float h2f(unsigned short u) {
  return __half2float(__ushort_as_half(u));
}
__device__ __forceinline__ float2 unpackh2(uint32_t u) {
  return make_float2(__half2float(__ushort_as_half((unsigned short)(u & 0xffffu))),
                     __half2float(__ushort_as_half((unsigned short)(u >> 16))));
}

__device__ __forceinline__ void gload_lds16(const void* g, void* s) {
  __builtin_amdgcn_global_load_lds(
      (const __attribute__((address_space(1))) uint32_t*)g,
      (__attribute__((address_space(3))) uint32_t*)s, 16, 0, 0);
}

// ---------------------------------------------------------------------------
// K0: per-column adjacency lists (ascending m, ballot compaction).
// 4 columns per block (one per wave) for occupancy.
__global__ __launch_bounds__(256) void k_collist(const float* __restrict__ adj,
                                                 int* __restrict__ col_idx,
                                                 int* __restrict__ col_cnt) {
  const int n = blockIdx.x * 4 + (threadIdx.x >> 6);
  const int lane = threadIdx.x & 63;
  int cnt = 0;
  for (int m0 = 0; m0 < NN; m0 += 64) {
    const int m = m0 + lane;
    const float a = adj[(size_t)m * NN + n];
    unsigned long long mask = __ballot(a != 0.0f);
    const int prefix = __popcll(mask & ((1ull << lane) - 1ull));
    if (a != 0.0f && cnt + prefix < MAXC) col_idx[n * MAXC + cnt + prefix] = m;
    cnt += __popcll(mask);
  }
  if (lane == 0) col_cnt[n] = (cnt > MAXC) ? MAXC : cnt;
}

// K0b: packed W sub-blocks + per-block prefix scan. 4 waves split the ji-loop.
__global__ __launch_bounds__(256) void k_wsub(const float* __restrict__ W,
                                              const int* __restrict__ col_idx,
                                              const int* __restrict__ col_cnt,
                                              int* __restrict__ col_off,
                                              float* __restrict__ Wsub) {
  const int n = blockIdx.x;
  const int t = threadIdx.x;
  const int wave = t >> 6, lane = t & 63;
  __shared__ int lsh[MAXC];
  __shared__ int preSh;
  const int c = col_cnt[n];
  if (wave == 0) {
    int pre = 0;
#pragma unroll
    for (int i0 = 0; i0 < NN; i0 += 64) {
      const int i = i0 + lane;
      const int cc = col_cnt[i];
      pre += (i < n) ? cc * cc : 0;
    }
#pragma unroll
    for (int off = 32; off; off >>= 1) pre += __shfl_xor(pre, off);
    if (lane == 0) { col_off[n] = pre; preSh = pre; }
    if (lane < c) lsh[lane] = col_idx[n * MAXC + lane];
  }
  __syncthreads();
  if (lane < c) {
    const float* Wm = W + (size_t)lsh[lane] * NN;
    float* dst = Wsub + preSh + lane;
    for (int ji = wave; ji < c; ji += 4)
      dst[(size_t)ji * c] = Wm[lsh[ji]];
  }
}

// ---------------------------------------------------------------------------
// K1: fused x-prep: x (B,S,N) f32 -> xp (B*S,512) f16, xt (B,N,S) f16,
//     plus zero-fill of the Att output region.
__global__ __launch_bounds__(256) void k_xprep(const float* __restrict__ x,
                                               unsigned short* __restrict__ xp,
                                               unsigned short* __restrict__ xt,
                                               float* __restrict__ Att) {
  __shared__ float tile[32][33];
  const int b = blockIdx.z;
  const int s0 = blockIdx.x * 32, n0 = blockIdx.y * 32;
  const float* xb = x + (size_t)b * SS * NN;
  const int tx = threadIdx.x, ty = threadIdx.y;  // (32,8)
#pragma unroll
  for (int i = ty; i < 32; i += 8) {
    const float v = xb[(size_t)(s0 + i) * NN + n0 + tx];
    tile[i][tx] = v;
    xp[(size_t)(b * SS + s0 + i) * 512 + n0 + tx] = f2h(v);
  }
  {
    const int bid = (blockIdx.z * 16 + blockIdx.y) * 8 + blockIdx.x;
    const int t = ty * 32 + tx;
    f32x4* dst = (f32x4*)(Att + (size_t)bid * 2048);
    const f32x4 z = (f32x4)0.0f;
    dst[t] = z;
    dst[t + 256] = z;
  }
  __syncthreads();
  unsigned short* xtb = xt + (size_t)b * NN * SS;
#pragma unroll
  for (int i = ty; i < 32; i += 8)
    xtb[(size_t)(n0 + i) * SS + s0 + tx] = f2h(tile[tx][i]);
}

// K1b: weight conversion to f16 (both Wq and Wk)
__global__ __launch_bounds__(128) void k_wsplit(const float* __restrict__ Wq,
                                                const float* __restrict__ Wk,
                                                unsigned short* __restrict__ Wqp,
                                                unsigned short* __restrict__ Wkp) {
  const int n = blockIdx.x;
  const float* src = blockIdx.y ? Wk : Wq;
  unsigned short* dst = blockIdx.y ? Wkp : Wqp;
  const int k = threadIdx.x * 4;
  float4 v = *(const float4*)(src + (size_t)n * NN + k);
  ushort4 o;
  o.x = f2h(v.x); o.y = f2h(v.y); o.z = f2h(v.z); o.w = f2h(v.w);
  *(ushort4*)(dst + (size_t)n * 512 + k) = o;
}

// ---------------------------------------------------------------------------
// K3: BOTH Linears in one block (shared X staging), 2-phase prefetch pipeline.
// Single-pass f16 GEMM (K=512 -> 16 K-steps). Q out f16, K out f16.
__global__ __launch_bounds__(256, 2) void k_lin2(const unsigned short* __restrict__ Wqp,
                                                 const unsigned short* __restrict__ Wkp,
                                                 const float* __restrict__ bq,
                                                 const float* __restrict__ bk,
                                                 const unsigned short* __restrict__ xp,
                                                 unsigned short* __restrict__ Qt,
                                                 unsigned short* __restrict__ Kt) {
  __shared__ __align__(16) char sm[49152];
  const int t = threadIdx.x;
  const int w = t >> 6, l = t & 63;
  const int id = blockIdx.x;
  const int xcd = id & 7, sub = id >> 3;
  const int bn0 = (xcd * 16 + (sub >> 2)) * 128;  // r = b*256+s
  const int bm0 = (sub & 3) * 128;                // n

  const int swz = (((l & 3) ^ ((l >> 3) & 3))) * 16;
  const char* srcb[6];
  char* dstb[6];
#pragma unroll
  for (int i = 0; i < 6; i++) {
    const int ch = w * 6 + i;
    const int panel = ch >> 3, rowgrp = ch & 7;
    const int row = rowgrp * 16 + (l >> 2);
    const char* g0 = (panel == 0) ? (const char*)Wqp
                   : (panel == 1) ? (const char*)Wkp : (const char*)xp;
    const int gr = ((panel == 2) ? bn0 : bm0) + row;
    srcb[i] = g0 + (size_t)gr * 1024 + swz;
    dstb[i] = sm + panel * 8192 + rowgrp * 1024 + l * 16;
  }

  const int fr = l & 15, fg = l >> 4;
  const int mrow = (w >> 1) * 64, ncol = (w & 1) * 64;
  const int slot = (fg ^ ((fr >> 1) & 3)) * 16;
  int offQ[4], offK[4], offB[4];
#pragma unroll
  for (int fm = 0; fm < 4; fm++) {
    offQ[fm] = (mrow + fm * 16 + fr) * 64 + slot;
    offK[fm] = 8192 + (mrow + fm * 16 + fr) * 64 + slot;
    offB[fm] = 16384 + (ncol + fm * 16 + fr) * 64 + slot;
  }

  f32x4 accq[4][4], acck[4][4];
#pragma unroll
  for (int i = 0; i < 4; i++)
#pragma unroll
    for (int j = 0; j < 4; j++) { accq[i][j] = (f32x4)0.0f; acck[i][j] = (f32x4)0.0f; }

#pragma unroll
  for (int i = 0; i < 6; i++) gload_lds16(srcb[i], dstb[i]);
  __syncthreads();

  int cur = 0;
  for (int kk = 0; kk < 16; kk++) {
    if (kk + 1 < 16) {
      const int ko = (kk + 1) * 64;
      const int boff = (cur ^ 1) * 24576;
#pragma unroll
      for (int i = 0; i < 6; i++)
        gload_lds16(srcb[i] + ko, dstb[i] + boff);
    }
    const char* base = sm + cur * 24576;
    half8 afq[4], afk[4];
#pragma unroll
    for (int fm = 0; fm < 4; fm++) {
      afq[fm] = *(const half8*)(base + offQ[fm]);
      afk[fm] = *(const half8*)(base + offK[fm]);
    }
#pragma unroll
    for (int fn = 0; fn < 4; fn++) {
      const half8 bv = *(const half8*)(base + offB[fn]);
#pragma unroll
      for (int fm = 0; fm < 4; fm++) {
        accq[fm][fn] = __builtin_amdgcn_mfma_f32_16x16x32_f16(afq[fm], bv, accq[fm][fn], 0, 0, 0);
        acck[fm][fn] = __builtin_amdgcn_mfma_f32_16x16x32_f16(afk[fm], bv, acck[fm][fn], 0, 0, 0);
      }
    }
    __syncthreads();
    cur ^= 1;
  }

  // epilogue: D col = lane&15 (-> r), row = (lane>>4)*4+q (-> n)
  const int b = bn0 >> 8;
  const int sbase = (bn0 & 255) + ncol;
#pragma unroll
  for (int fm = 0; fm < 4; fm++) {
#pragma unroll
    for (int q = 0; q < 4; q++) {
      const int n = bm0 + mrow + fm * 16 + fg * 4 + q;
      const float bvq = bq[n];
      const float bvk = bk[n];
#pragma unroll
      for (int fn = 0; fn < 4; fn++) {
        const int s = sbase + fn * 16 + fr;
        Qt[((size_t)b * NN + n) * SS + s] = f2h(accq[fm][fn][q] + bvq);
        Kt[((size_t)b * NN + n) * SS + s] = f2h(acck[fm][fn][q] + bvk);
      }
    }
  }
}

// ---------------------------------------------------------------------------
// K3b: dense Gram per batch: ST[b][n][j] = <Q[b,n,:], K[b,j,:]>, f16 out.
// NT GEMM, M=N=512, K=256; 128x128 tile, BK=32, 2-phase prefetch.
__global__ __launch_bounds__(256, 2) void k_gram(const unsigned short* __restrict__ Qt,
                                                 const unsigned short* __restrict__ Kt,
                                                 unsigned short* __restrict__ ST) {
  __shared__ __align__(16) char sm[32768];
  const int t = threadIdx.x;
  const int w = t >> 6, l = t & 63;
  const int id = blockIdx.x;
  const int xcd = id & 7, rest = id >> 3;       // rest 0..127
  const int batch = (xcd << 3) + (rest >> 4);   // 8 batches per XCD, 16 tiles each
  const int tile = rest & 15;
  const int m0 = (tile >> 2) * 128;             // n rows (A = Q)
  const int n0 = (tile & 3) * 128;              // j rows (B = K)

  const int swz = (((l & 3) ^ ((l >> 3) & 3))) * 16;
  const char* srcb[4];
  char* dstb[4];
#pragma unroll
  for (int i = 0; i < 4; i++) {
    const int ch = w * 4 + i;                   // 16 chunks: A(0..7), B(8..15)
    const int panel = ch >> 3, rowgrp = ch & 7;
    const int row = rowgrp * 16 + (l >> 2);
    const char* g0 = panel ? (const char*)Kt : (const char*)Qt;
    const int gr = (panel ? n0 : m0) + row;
    srcb[i] = g0 + ((size_t)batch * 512 + gr) * 512 + swz;
    dstb[i] = sm + panel * 8192 + rowgrp * 1024 + l * 16;
  }

  const int fr = l & 15, fg = l >> 4;
  const int mrow = (w >> 1) * 64, ncol = (w & 1) * 64;
  const int slot = (fg ^ ((fr >> 1) & 3)) * 16;
  int offA[4], offB[4];
#pragma unroll
  for (int fm = 0; fm < 4; fm++) {
    offA[fm] = (mrow + fm * 16 + fr) * 64 + slot;
    offB[fm] = 8192 + (ncol + fm * 16 + fr) * 64 + slot;
  }

  f32x4 acc[4][4];
#pragma unroll
  for (int i = 0; i < 4; i++)
#pragma unroll
    for (int j = 0; j < 4; j++) acc[i][j] = (f32x4)0.0f;

#pragma unroll
  for (int i = 0; i < 4; i++) gload_lds16(srcb[i], dstb[i]);
  __syncthreads();

  int cur = 0;
  for (int kk = 0; kk < 8; kk++) {
    if (kk + 1 < 8) {
      const int ko = (kk + 1) * 64;
      const int boff = (cur ^ 1) * 16384;
#pragma unroll
      for (int i = 0; i < 4; i++)
        gload_lds16(srcb[i] + ko, dstb[i] + boff);
    }
    const char* base = sm + cur * 16384;
    half8 af[4];
#pragma unroll
    for (int fm = 0; fm < 4; fm++)
      af[fm] = *(const half8*)(base + offA[fm]);
#pragma unroll
    for (int fn = 0; fn < 4; fn++) {
      const half8 bv = *(const half8*)(base + offB[fn]);
#pragma unroll
      for (int fm = 0; fm < 4; fm++)
        acc[fm][fn] = __builtin_amdgcn_mfma_f32_16x16x32_f16(af[fm], bv, acc[fm][fn], 0, 0, 0);
    }
    __syncthreads();
    cur ^= 1;
  }

  // epilogue: D row -> n (A rows), D col -> j (B rows)
  unsigned short* STb = ST + (size_t)batch * NN * NN;
#pragma unroll
  for (int fm = 0; fm < 4; fm++) {
#pragma unroll
    for (int q = 0; q < 4; q++) {
      const int n = m0 + mrow + fm * 16 + fg * 4 + q;
#pragma unroll
      for (int fn = 0; fn < 4; fn++) {
        const int j = n0 + ncol + fn * 16 + fr;
        STb[(size_t)n * NN + j] = f2h(acc[fm][fn][q]);
      }
    }
  }
}

// ---------------------------------------------------------------------------
// K4: fused sparse stage — ONE WAVE per (n,b) column; 4 batches per block;
// one __syncthreads. Step 1 is now a single contiguous-row f16 gather from ST.
__global__ __launch_bounds__(256) void k_fused(const unsigned short* __restrict__ ST,
                                               const unsigned short* __restrict__ xt,
                                               const float* __restrict__ Wsub,
                                               const float* __restrict__ pnw,
                                               const int* __restrict__ col_idx,
                                               const int* __restrict__ col_cnt,
                                               const int* __restrict__ col_off,
                                               float* __restrict__ Att,
                                               float* __restrict__ agg) {
  // XCD-exclusive swizzle: xcd = id&7 owns batches [xcd*8, xcd*8+8).
  const int id = blockIdx.x;          // 0..8191
  const int xcd = id & 7;
  const int r = id >> 3;              // 0..1023
  const int n = r & 511;
  const int bgrp = r >> 9;            // 0..1
  const int t = threadIdx.x;
  const int wave = t >> 6, lane = t & 63;
  const int b = (xcd << 3) + (bgrp << 2) + wave;

  __shared__ int   lsh[MAXC + 1];
  __shared__ int   lshB[MAXC + 1];    // lsh * 512 (byte offset of a f16 row)
  __shared__ float Wsh[MAXC * MAXC];
  __shared__ float vsh[4][MAXC];
  __shared__ float ash[4][MAXC + 1];

  const int c = col_cnt[n];
  if (t < c) {
    const int v = col_idx[n * MAXC + t];
    lsh[t] = v;
    lshB[t] = v << 9;
  }
  if (t == c) { lsh[c] = n; lshB[c] = n << 9; }
  {
    const int cc = c * c;
    const float* Wp = Wsub + col_off[n];
    for (int i = t; i < cc; i += 256) Wsh[i] = Wp[i];
  }
  __syncthreads();   // the only block barrier

  // Step 1: v[ji] = ST[b][n][lsh[ji]] — one 2B load per lane from one row.
  const unsigned short* STrow = ST + ((size_t)b * NN + n) * NN;
  if (lane < c) vsh[wave][lane] = h2f(STrow[lsh[lane]]);
  // same-wave LDS: in-order DS pipe, no barrier needed.

  // Step 2: aval[mi] = sum_ji Wsh[ji*c+mi] * v[ji]  (lane = mi)
  float aval = 0.0f;
  if (lane < c) {
    for (int ji = 0; ji < c; ji++)
      aval += Wsh[ji * c + lane] * vsh[wave][ji];
  }

  // Step 3: in-wave softmax over {aval[0..c), pnw[n] at diag, 512-c-1 zeros}
  const float dlg = pnw[n];
  float mval = (lane < c) ? aval : -INFINITY;
#pragma unroll
  for (int off = 32; off; off >>= 1) mval = fmaxf(mval, __shfl_xor(mval, off));
  const float colmax = fmaxf(mval, fmaxf(dlg, 0.0f));
  const float e = (lane < c) ? __expf(aval - colmax) : 0.0f;
  float sum = e;
#pragma unroll
  for (int off = 32; off; off >>= 1) sum += __shfl_xor(sum, off);
  const float denom = sum + __expf(dlg - colmax)
                    + (float)(NN - c - 1) * __expf(-colmax);
  const float inv = 1.0f / denom;

  // Step 4/5: Att column scatter (rest of column stays zero-filled)
  float* Acol = Att + (size_t)b * NN * NN + n;
  if (lane < c) {
    const float attv = e * inv;
    ash[wave][lane] = attv;
    Acol[(size_t)lsh[lane] * NN] = attv;
  }
  if (lane == c) {
    const float dv = __expf(dlg - colmax) * inv;
    ash[wave][c] = dv;
    Acol[(size_t)n * NN] = dv;
  }

  // Step 6: agg[b,n,:] = sum_{mi<=c} ash[mi] * xt[b,lsh[mi],:]
  const char* xtb = (const char*)(xt + (size_t)b * NN * SS);
  f32x4 acc = (f32x4)0.0f;
  for (int mi = 0; mi <= c; mi++) {
    const float a = ash[wave][mi];
    const uint2 v = *(const uint2*)(xtb + lshB[mi] + lane * 8);
    const float2 x01 = unpackh2(v.x);
    const float2 x23 = unpackh2(v.y);
    acc.x += a * x01.x;
    acc.y += a * x01.y;
    acc.z += a * x23.x;
    acc.w += a * x23.y;
  }
  *(f32x4*)(agg + ((size_t)b * NN + n) * SS + lane * 4) = acc;
}

// ---------------------------------------------------------------------------
extern "C" void kernel_launch(void* const* d_in, const int* in_sizes, int n_in,
                              void* d_out, int out_size, void* d_ws, size_t ws_size,
                              hipStream_t stream) {
  const float* x    = (const float*)d_in[0];
  const float* adj  = (const float*)d_in[1];
  const float* W    = (const float*)d_in[2];
  const float* pnw  = (const float*)d_in[3];
  const float* Wq_w = (const float*)d_in[4];
  const float* Wq_b = (const float*)d_in[5];
  const float* Wk_w = (const float*)d_in[6];
  const float* Wk_b = (const float*)d_in[7];

  float* agg = (float*)d_out;                        // (B,N,S)
  float* Att = (float*)d_out + (size_t)BB * NN * SS; // (B,N,N)

  char* p = (char*)d_ws;
  unsigned short* xp  = (unsigned short*)p; p += (size_t)BB * SS * 512 * 2;   // 16.78 MB (f16)
  unsigned short* Wqp = (unsigned short*)p; p += (size_t)NN * 512 * 2;        // 0.52 MB
  unsigned short* Wkp = (unsigned short*)p; p += (size_t)NN * 512 * 2;        // 0.52 MB
  unsigned short* Qt  = (unsigned short*)p; p += (size_t)BB * NN * SS * 2;    // 16.78 MB (f16)
  unsigned short* Kt  = (unsigned short*)p; p += (size_t)BB * NN * SS * 2;    // 16.78 MB (f16)
  unsigned short* xt  = (unsigned short*)p; p += (size_t)BB * NN * SS * 2;    // 16.78 MB (f16)
  unsigned short* ST  = (unsigned short*)p; p += (size_t)BB * NN * NN * 2;    // 33.55 MB (f16)
  float* Wsub = (float*)p; p += (size_t)NN * MAXC * MAXC * 4;                 // 8.39 MB (bound)
  int* col_idx = (int*)p; p += (size_t)NN * MAXC * 4;
  int* col_cnt = (int*)p; p += NN * 4;
  int* col_off = (int*)p;

  k_collist<<<dim3(NN / 4), dim3(256), 0, stream>>>(adj, col_idx, col_cnt);
  k_wsub<<<dim3(NN), dim3(256), 0, stream>>>(W, col_idx, col_cnt, col_off, Wsub);
  k_xprep<<<dim3(SS / 32, NN / 32, BB), dim3(32, 8), 0, stream>>>(x, xp, xt, Att);
  k_wsplit<<<dim3(NN, 2), dim3(128), 0, stream>>>(Wq_w, Wk_w, Wqp, Wkp);

  k_lin2<<<dim3(512), dim3(256), 0, stream>>>(Wqp, Wkp, Wq_b, Wk_b, xp, Qt, Kt);
  k_gram<<<dim3(1024), dim3(256), 0, stream>>>(Qt, Kt, ST);
  k_fused<<<dim3(8192), dim3(256), 0, stream>>>(ST, xt, Wsub, pnw,
                                                col_idx, col_cnt, col_off,
                                                Att, agg);
}